// Round 4
// baseline (2318.988 us; speedup 1.0000x reference)
//
#include <hip/hip_runtime.h>
#include <math.h>

#define LNUM 6
#define HNUM 12
#define CDIM 768
#define VDIM 50257
#define BDIM 4
#define TDIM 1024
#define NTOK 4096   // B*T

typedef __bf16 bf16;
typedef __bf16 bf16x8 __attribute__((ext_vector_type(8)));
typedef float  floatx4 __attribute__((ext_vector_type(4)));
typedef unsigned int u32;

// async global->LDS, 16B per lane. LDS dest must be wave-uniform base; HW adds lane*16.
__device__ inline void gload16(const bf16* gsrc, bf16* lds) {
  __builtin_amdgcn_global_load_lds(
      (const __attribute__((address_space(1))) u32*)gsrc,
      (__attribute__((address_space(3))) u32*)lds, 16, 0, 0);
}

// ---------------- fp32 -> bf16 bulk convert (wte) ----------------
__global__ void k_cvt_bf16(const float* __restrict__ in, bf16* __restrict__ out, long n) {
  long i = ((long)blockIdx.x * blockDim.x + threadIdx.x) * 4;
  long stride = (long)gridDim.x * blockDim.x * 4;
  for (; i < n; i += stride) {
    float4 v = *reinterpret_cast<const float4*>(in + i);
    bf16 b0 = (bf16)v.x, b1 = (bf16)v.y, b2 = (bf16)v.z, b3 = (bf16)v.w;
    ushort4 pk;
    pk.x = __builtin_bit_cast(unsigned short, b0);
    pk.y = __builtin_bit_cast(unsigned short, b1);
    pk.z = __builtin_bit_cast(unsigned short, b2);
    pk.w = __builtin_bit_cast(unsigned short, b3);
    *reinterpret_cast<ushort4*>(out + i) = pk;
  }
}

// -------- batched transpose+convert for ALL layer weights (one launch) --------
// fp32 [K,N] -> bf16 [N,K]; 6 layers x {qkv, proj, fc, fcp}
#define TILES_QKV  1728   // (2304/32)*(768/32)
#define TILES_PROJ 576
#define TILES_FC   2304
#define TILES_FCP  2304
#define TILES_LAYER (TILES_QKV + TILES_PROJ + TILES_FC + TILES_FCP)

__global__ __launch_bounds__(256) void k_trans_all(
    const float* __restrict__ qkv_w, const float* __restrict__ proj_w,
    const float* __restrict__ fc_w, const float* __restrict__ fcp_w,
    bf16* __restrict__ wq, bf16* __restrict__ wp,
    bf16* __restrict__ wf, bf16* __restrict__ wfp) {
  __shared__ float tile[32][33];
  int bid = blockIdx.x;
  int layer = bid / TILES_LAYER, r = bid % TILES_LAYER;
  const float* src; bf16* dst; int K, N, tx, ty;
  if (r < TILES_QKV) {
    src = qkv_w + (size_t)layer * CDIM * 3 * CDIM; dst = wq + (size_t)layer * CDIM * 3 * CDIM;
    K = CDIM; N = 3 * CDIM; tx = r % 72; ty = r / 72;
  } else if (r < TILES_QKV + TILES_PROJ) {
    r -= TILES_QKV;
    src = proj_w + (size_t)layer * CDIM * CDIM; dst = wp + (size_t)layer * CDIM * CDIM;
    K = CDIM; N = CDIM; tx = r % 24; ty = r / 24;
  } else if (r < TILES_QKV + TILES_PROJ + TILES_FC) {
    r -= TILES_QKV + TILES_PROJ;
    src = fc_w + (size_t)layer * CDIM * 4 * CDIM; dst = wf + (size_t)layer * CDIM * 4 * CDIM;
    K = CDIM; N = 4 * CDIM; tx = r % 96; ty = r / 96;
  } else {
    r -= TILES_QKV + TILES_PROJ + TILES_FC;
    src = fcp_w + (size_t)layer * 4 * CDIM * CDIM; dst = wfp + (size_t)layer * 4 * CDIM * CDIM;
    K = 4 * CDIM; N = CDIM; tx = r % 24; ty = r / 24;
  }
  int n0 = tx * 32, k0 = ty * 32;
  int nx = threadIdx.x & 31, tyy = threadIdx.x >> 5;
  #pragma unroll
  for (int p = 0; p < 4; ++p) {
    int k = tyy + p * 8;
    tile[k][nx] = src[(size_t)(k0 + k) * N + n0 + nx];
  }
  __syncthreads();
  #pragma unroll
  for (int p = 0; p < 4; ++p) {
    int n = tyy + p * 8;
    dst[(size_t)(n0 + n) * K + k0 + nx] = (bf16)tile[nx][n];
  }
}

// ---------------- embedding ----------------
__global__ void k_embed(const int* __restrict__ idx, const float* __restrict__ wte,
                        const float* __restrict__ wpe, float* __restrict__ x) {
  int tok = blockIdx.x;
  int t = tok & (TDIM - 1);
  int id = idx[tok];
  const float* a = wte + (size_t)id * CDIM;
  const float* p = wpe + (size_t)t * CDIM;
  float* o = x + (size_t)tok * CDIM;
  for (int c = threadIdx.x; c < CDIM; c += 256) o[c] = a[c] + p[c];
}

// ---------------- layernorm: fp32 in -> bf16 out ----------------
__global__ __launch_bounds__(256) void k_layernorm(const float* __restrict__ x,
    const float* __restrict__ sc, const float* __restrict__ bi, bf16* __restrict__ out) {
  __shared__ float red[8];
  int row = blockIdx.x;
  const float* xr = x + (size_t)row * CDIM;
  int t = threadIdx.x;
  float v0 = xr[t], v1 = xr[t + 256], v2 = xr[t + 512];
  float s = v0 + v1 + v2;
  #pragma unroll
  for (int o = 32; o > 0; o >>= 1) s += __shfl_down(s, o);
  if ((t & 63) == 0) red[t >> 6] = s;
  __syncthreads();
  float mean = (red[0] + red[1] + red[2] + red[3]) * (1.0f / CDIM);
  float d0 = v0 - mean, d1 = v1 - mean, d2 = v2 - mean;
  float q = d0 * d0 + d1 * d1 + d2 * d2;
  #pragma unroll
  for (int o = 32; o > 0; o >>= 1) q += __shfl_down(q, o);
  if ((t & 63) == 0) red[4 + (t >> 6)] = q;
  __syncthreads();
  float var = (red[4] + red[5] + red[6] + red[7]) * (1.0f / CDIM);
  float rs = rsqrtf(var + 1e-5f);
  bf16* orow = out + (size_t)row * CDIM;
  orow[t]       = (bf16)(d0 * rs * sc[t]       + bi[t]);
  orow[t + 256] = (bf16)(d1 * rs * sc[t + 256] + bi[t + 256]);
  orow[t + 512] = (bf16)(d2 * rs * sc[t + 512] + bi[t + 512]);
}

__device__ inline float gelu_f(float x) {
  float x3 = x * x * x;
  return 0.5f * x * (1.0f + tanhf(0.7978845608028654f * (x + 0.044715f * x3)));
}

// ================= 256x256 8-phase MFMA GEMM =================
// C[4096,N] = A[4096,K] * Bt[N,K]^T.  BM=BN=256, BK=64, 512 threads (8 waves, 2Mx4N).
// LDS: 2 buffers x 4 K-split regions {B@kk0, A@kk0, B@kk1, A@kk1}, each [256][32] bf16.
// Static phase->stage map (tile t): ph0: A+(t+1)*64+32 -> [t+1][3]; ph1: B+(t+2)*64 -> [t][0];
// ph2: A+(t+2)*64 -> [t][1]; ph3: B+(t+2)*64+32 -> [t][2].  (region-death verified)
// vmcnt(6) per tile (3 halves x 2 loads in flight); vmcnt(0) when prefetch stops. numK >= 2.
// EPI: 0 ->f32 nontemporal (no bias, N-tail guard), 3 +bias+gelu ->bf16, 4 +bias ->bf16
template<int EPI>
__global__ __launch_bounds__(512, 1) void k_gemm8(
    const bf16* __restrict__ A, const bf16* __restrict__ Bt,
    const float* __restrict__ bias,
    float* __restrict__ Cf, bf16* __restrict__ Cb,
    int N, int K) {
  __shared__ __align__(16) bf16 lds[2][4][8192];
  const int nwg = gridDim.x;                      // divisible by 8
  const int id = blockIdx.x;
  const int swz = (id & 7) * (nwg >> 3) + (id >> 3);   // XCD-chunked (bijective, nwg%8==0)
  const int m0 = (swz & 15) * 256;
  const int n0 = (swz >> 4) * 256;
  const int tid = threadIdx.x, lane = tid & 63, wave = tid >> 6;
  const int wr = wave >> 2, wc = wave & 3;        // wave grid 2(M) x 4(N)
  const int g = lane >> 4, r16 = lane & 15;
  const int numK = K >> 6;
  const int wsl = wave * 512;

  const int srow = wave * 16 + (lane >> 2);
  const int scol = (lane & 3) * 8;
  const bf16* at  = A  + (size_t)(m0 + srow) * K + scol;
  const bf16* at1 = A  + (size_t)(m0 + srow + 128) * K + scol;
  const bf16* bt  = Bt + (size_t)(n0 + srow) * K + scol;
  const bf16* bt1 = Bt + (size_t)(n0 + srow + 128) * K + scol;
  const int a_off = (wr * 128 + r16) * 32 + g * 8;
  const int b_off = (wc * 64 + r16) * 32 + g * 8;

  floatx4 acc[8][4] = {};

#define G2(sA, sB, dst) do { gload16((sA), (dst)); gload16((sB), (dst) + 4096); } while (0)

  // prologue: tile0 full (H0-3) + 3 halves of tile1 (H4-6)
  G2(bt,      bt1,      &lds[0][0][wsl]);
  G2(at,      at1,      &lds[0][1][wsl]);
  G2(bt + 32, bt1 + 32, &lds[0][2][wsl]);
  G2(at + 32, at1 + 32, &lds[0][3][wsl]);
  G2(bt + 64, bt1 + 64, &lds[1][0][wsl]);
  G2(at + 64, at1 + 64, &lds[1][1][wsl]);
  G2(bt + 96, bt1 + 96, &lds[1][2][wsl]);
  asm volatile("s_waitcnt vmcnt(6)" ::: "memory");   // tile0's 8 loads landed
  __builtin_amdgcn_s_barrier();

  for (int t = 0; t < numK; ++t) {
    const int p = t & 1, pn = p ^ 1;
    bf16x8 af[4], bfr[4];

    // ---- phase 0: kk=0, mgroup 0 ----
    #pragma unroll
    for (int j = 0; j < 4; ++j) bfr[j] = *(const bf16x8*)&lds[p][0][b_off + j * 512];
    #pragma unroll
    for (int i = 0; i < 4; ++i) af[i] = *(const bf16x8*)&lds[p][1][a_off + i * 512];
    if (t + 1 < numK) G2(at + 96, at1 + 96, &lds[pn][3][wsl]);
    __builtin_amdgcn_s_barrier();
    asm volatile("s_waitcnt lgkmcnt(0)" ::: "memory");
    __builtin_amdgcn_s_setprio(1);
    #pragma unroll
    for (int i = 0; i < 4; ++i)
      #pragma unroll
      for (int j = 0; j < 4; ++j)
        acc[i][j] = __builtin_amdgcn_mfma_f32_16x16x32_bf16(af[i], bfr[j], acc[i][j], 0, 0, 0);
    __builtin_amdgcn_s_setprio(0);
    __builtin_amdgcn_s_barrier();

    // ---- phase 1: kk=0, mgroup 1 (B regs reused) ----
    #pragma unroll
    for (int i = 0; i < 4; ++i) af[i] = *(const bf16x8*)&lds[p][1][a_off + (i + 4) * 512];
    if (t + 2 < numK) G2(bt + 128, bt1 + 128, &lds[p][0][wsl]);
    __builtin_amdgcn_s_barrier();
    asm volatile("s_waitcnt lgkmcnt(0)" ::: "memory");
    __builtin_amdgcn_s_setprio(1);
    #pragma unroll
    for (int i = 0; i < 4; ++i)
      #pragma unroll
      for (int j = 0; j < 4; ++j)
        acc[i + 4][j] = __builtin_amdgcn_mfma_f32_16x16x32_bf16(af[i], bfr[j], acc[i + 4][j], 0, 0, 0);
    __builtin_amdgcn_s_setprio(0);
    __builtin_amdgcn_s_barrier();

    // ---- phase 2: kk=1, mgroup 0 ----
    #pragma unroll
    for (int j = 0; j < 4; ++j) bfr[j] = *(const bf16x8*)&lds[p][2][b_off + j * 512];
    #pragma unroll
    for (int i = 0; i < 4; ++i) af[i] = *(const bf16x8*)&lds[p][3][a_off + i * 512];
    if (t + 2 < numK) G2(at + 128, at1 + 128, &lds[p][1][wsl]);
    __builtin_amdgcn_s_barrier();
    asm volatile("s_waitcnt lgkmcnt(0)" ::: "memory");
    __builtin_amdgcn_s_setprio(1);
    #pragma unroll
    for (int i = 0; i < 4; ++i)
      #pragma unroll
      for (int j = 0; j < 4; ++j)
        acc[i][j] = __builtin_amdgcn_mfma_f32_16x16x32_bf16(af[i], bfr[j], acc[i][j], 0, 0, 0);
    __builtin_amdgcn_s_setprio(0);
    __builtin_amdgcn_s_barrier();

    // ---- phase 3: kk=1, mgroup 1 (B regs reused) ----
    #pragma unroll
    for (int i = 0; i < 4; ++i) af[i] = *(const bf16x8*)&lds[p][3][a_off + (i + 4) * 512];
    if (t + 2 < numK) G2(bt + 160, bt1 + 160, &lds[p][2][wsl]);
    __builtin_amdgcn_s_barrier();
    asm volatile("s_waitcnt lgkmcnt(0)" ::: "memory");
    __builtin_amdgcn_s_setprio(1);
    #pragma unroll
    for (int i = 0; i < 4; ++i)
      #pragma unroll
      for (int j = 0; j < 4; ++j)
        acc[i + 4][j] = __builtin_amdgcn_mfma_f32_16x16x32_bf16(af[i], bfr[j], acc[i + 4][j], 0, 0, 0);
    __builtin_amdgcn_s_setprio(0);
    if (t + 2 < numK) { asm volatile("s_waitcnt vmcnt(6)" ::: "memory"); }
    else              { asm volatile("s_waitcnt vmcnt(0)" ::: "memory"); }
    __builtin_amdgcn_s_barrier();

    at += 64; at1 += 64; bt += 64; bt1 += 64;
  }
#undef G2

  // ---------------- epilogue ----------------
  // C/D layout: col = lane&15, row = (lane>>4)*4 + reg
  if (EPI == 0) {
    const int mb = m0 + wr * 128 + g * 4;
    const int nb = n0 + wc * 64 + r16;
    #pragma unroll
    for (int nf = 0; nf < 4; ++nf) {
      int n = nb + nf * 16;
      if (n >= N) continue;
      #pragma unroll
      for (int mf = 0; mf < 8; ++mf) {
        #pragma unroll
        for (int q = 0; q < 4; ++q) {
          int m = mb + mf * 16 + q;
          __builtin_nontemporal_store(acc[mf][nf][q], &Cf[(size_t)m * N + n]);
        }
      }
    }
  } else {
    // wave-private LDS transpose -> 16B bf16x8 stores (full cache lines)
    bf16* sb = &lds[0][0][0] + wave * 1152;   // 16 rows x 72 stride
    const int rr_rd = lane & 15, seg = lane >> 4;
    const int nb = n0 + wc * 64 + r16;
    float bv[4];
    #pragma unroll
    for (int j = 0; j < 4; ++j) bv[j] = bias[nb + j * 16];
    #pragma unroll
    for (int mf = 0; mf < 8; ++mf) {
      #pragma unroll
      for (int j = 0; j < 4; ++j) {
        #pragma unroll
        for (int q = 0; q < 4; ++q) {
          float v = acc[mf][j][q] + bv[j];
          if (EPI == 3) v = gelu_f(v);
          sb[(g * 4 + q) * 72 + j * 16 + r16] = (bf16)v;
        }
      }
      bf16x8 o0 = *(const bf16x8*)&sb[rr_rd * 72 + seg * 16];
      bf16x8 o1 = *(const bf16x8*)&sb[rr_rd * 72 + seg * 16 + 8];
      size_t orow = (size_t)(m0 + wr * 128 + mf * 16 + rr_rd) * N + (n0 + wc * 64 + seg * 16);
      *(bf16x8*)&Cb[orow] = o0;
      *(bf16x8*)&Cb[orow + 8] = o1;
    }
  }
}

// ---------------- legacy 2-phase NT GEMM (proj / fcp: N=768) ----------------
template<int TBM, int MI, int NI, int EPI>
__global__ __launch_bounds__(256) void k_gemm(
    const bf16* __restrict__ A, const bf16* __restrict__ Bt,
    const float* __restrict__ bias, const float* __restrict__ resid,
    float* __restrict__ Cf, bf16* __restrict__ Cb,
    int M, int N, int K) {
  constexpr int BN = 128;
  constexpr int WGN = BN / (NI * 16);
  constexpr int AI = TBM / 32;
  constexpr int BI = BN / 32;
  __shared__ __align__(16) bf16 As[TBM * 64];
  __shared__ __align__(16) bf16 Bs[BN * 64];
  const int m0 = blockIdx.x * TBM, n0 = blockIdx.y * BN;
  const int tid = threadIdx.x;
  const int lane = tid & 63, wave = tid >> 6;
  const int wr = wave / WGN, wc = wave % WGN;
  const int l8 = lane >> 3, s8 = lane & 7;
  const int g = lane >> 4, r16 = lane & 15;

  floatx4 acc[MI][NI] = {};

  const bf16* a_src = A + (size_t)(m0 + l8) * K + s8 * 8;
  const bf16* b_src = Bt + (size_t)(n0 + l8) * K + s8 * 8;

  for (int k0 = 0; k0 < K; k0 += 64) {
    #pragma unroll
    for (int t = 0; t < AI; ++t) {
      int row0 = wave * (TBM / 4) + t * 8;
      gload16(a_src + (size_t)row0 * K + k0, &As[row0 * 64]);
    }
    #pragma unroll
    for (int t = 0; t < BI; ++t) {
      int row0 = wave * 32 + t * 8;
      gload16(b_src + (size_t)row0 * K + k0, &Bs[row0 * 64]);
    }
    __syncthreads();
    #pragma unroll
    for (int kk = 0; kk < 2; ++kk) {
      bf16x8 af[MI], bfr[NI];
      #pragma unroll
      for (int i = 0; i < MI; ++i)
        af[i] = *reinterpret_cast<const bf16x8*>(&As[(wr * MI * 16 + i * 16 + r16) * 64 + g * 8 + kk * 32]);
      #pragma unroll
      for (int j = 0; j < NI; ++j)
        bfr[j] = *reinterpret_cast<const bf16x8*>(&Bs[(wc * NI * 16 + j * 16 + r16) * 64 + g * 8 + kk * 32]);
      #pragma unroll
      for (int i = 0; i < MI; ++i) {
        #pragma unroll
        for (int j = 0; j < NI; ++j)
          acc[i][j] = __builtin_amdgcn_mfma_f32_16x16x32_bf16(af[i], bfr[j], acc[i][j], 0, 0, 0);
      }
    }
    __syncthreads();
  }

  int mb = m0 + wr * MI * 16 + g * 4;
  int nb = n0 + wc * NI * 16 + r16;
  #pragma unroll
  for (int j = 0; j < NI; ++j) {
    int n = nb + j * 16;
    if (n >= N) continue;
    float bv = (EPI >= 2) ? bias[n] : 0.0f;
    #pragma unroll
    for (int i = 0; i < MI; ++i) {
      #pragma unroll
      for (int q = 0; q < 4; ++q) {
        int m = mb + i * 16 + q;
        float v = acc[i][j][q] + bv;
        size_t o = (size_t)m * N + n;
        if (EPI == 2)      Cf[o] = v + resid[o];
        else if (EPI == 3) Cb[o] = (bf16)gelu_f(v);
        else if (EPI == 4) Cb[o] = (bf16)v;
        else               Cf[o] = v;
      }
    }
  }
}

// ---------------- V transpose: qkv_bf V-part -> vt[bh][d][t] bf16 ----------------
__global__ __launch_bounds__(256) void k_vtrans(const bf16* __restrict__ qkv, bf16* __restrict__ vt) {
  __shared__ bf16 tile[64][72];
  int bh = blockIdx.x, t0 = blockIdx.y * 64;
  int b = bh / HNUM, h = bh % HNUM;
  int tid = threadIdx.x;
  int r8 = tid >> 3, s8 = tid & 7;
  #pragma unroll
  for (int p = 0; p < 2; ++p) {
    int row = p * 32 + r8;
    uint4 v = *reinterpret_cast<const uint4*>(
        qkv + (size_t)(b * TDIM + t0 + row) * (3 * CDIM) + 2 * CDIM + h * 64 + s8 * 8);
    *reinterpret_cast<uint4*>(&tile[row][s8 * 8]) = v;
  }
  __syncthreads();
  int d = tid >> 2, q4 = tid & 3;
  #pragma unroll
  for (int half = 0; half < 2; ++half) {
    int t = q4 * 16 + half * 8;
    bf16x8 o;
    #pragma unroll
    for (int u = 0; u < 8; ++u) o[u] = tile[t + u][d];
    *reinterpret_cast<bf16x8*>(vt + (size_t)bh * (64 * TDIM) + (size_t)d * TDIM + t0 + t) = o;
  }
}

// ---------------- MFMA flash attention ----------------
__global__ __launch_bounds__(256) void k_attn(const bf16* __restrict__ qkv,
                                              const bf16* __restrict__ vt,
                                              bf16* __restrict__ y) {
  __shared__ __align__(16) bf16 Ks[64 * 64];
  __shared__ __align__(16) bf16 Vs[64 * 64];
  __shared__ __align__(16) bf16 Ps[64 * 64];
  const int bh = blockIdx.x, qt = blockIdx.y;
  const int b = bh / HNUM, h = bh % HNUM;
  const int tid = threadIdx.x, lane = tid & 63, wave = tid >> 6;
  const int g = lane >> 4, r16 = lane & 15;
  const int w16 = wave * 16;
  const int r8 = tid >> 3, s8 = tid & 7;

  bf16x8 qf[2];
  {
    const bf16* qsrc = qkv + (size_t)(b * TDIM + qt * 64 + w16 + r16) * (3 * CDIM) + h * 64 + g * 8;
    qf[0] = *reinterpret_cast<const bf16x8*>(qsrc);
    qf[1] = *reinterpret_cast<const bf16x8*>(qsrc + 32);
  }

  float m_r[4], l_r[4];
  floatx4 yacc[4] = {};
  #pragma unroll
  for (int q = 0; q < 4; ++q) { m_r[q] = -1e30f; l_r[q] = 0.f; }

  for (int kt = 0; kt <= qt; ++kt) {
    __syncthreads();
    #pragma unroll
    for (int p = 0; p < 2; ++p) {
      int row = p * 32 + r8;
      uint4 kv = *reinterpret_cast<const uint4*>(
          qkv + (size_t)(b * TDIM + kt * 64 + row) * (3 * CDIM) + CDIM + h * 64 + s8 * 8);
      *reinterpret_cast<uint4*>(&Ks[row * 64 + ((s8 ^ (row & 7)) * 8)]) = kv;
      uint4 vv = *reinterpret_cast<const uint4*>(
          vt + (size_t)bh * (64 * TDIM) + (size_t)row * TDIM + kt * 64 + s8 * 8);
      *reinterpret_cast<uint4*>(&Vs[row * 64 + ((s8 ^ (row & 7)) * 8)]) = vv;
    }
    __syncthreads();

    floatx4 sa[4] = {};
    #pragma unroll
    for (int c = 0; c < 2; ++c) {
      bf16x8 kf[4];
      #pragma unroll
      for (int j = 0; j < 4; ++j) {
        int krow = j * 16 + r16;
        kf[j] = *reinterpret_cast<const bf16x8*>(&Ks[krow * 64 + (((g + 4 * c) ^ (krow & 7)) * 8)]);
      }
      #pragma unroll
      for (int j = 0; j < 4; ++j)
        sa[j] = __builtin_amdgcn_mfma_f32_16x16x32_bf16(qf[c], kf[j], sa[j], 0, 0, 0);
    }

    const bool diag = (kt == qt);
    float p_v[4][4];
    #pragma unroll
    for (int q = 0; q < 4; ++q) {
      int qrow = w16 + g * 4 + q;
      float mx = -1e30f;
      #pragma unroll
      for (int j = 0; j < 4; ++j) {
        float s = sa[j][q] * 0.125f;
        if (diag && (r16 + j * 16) > qrow) s = -1e30f;
        p_v[j][q] = s;
        mx = fmaxf(mx, s);
      }
      #pragma unroll
      for (int o = 1; o < 16; o <<= 1) mx = fmaxf(mx, __shfl_xor(mx, o));
      float mnew = fmaxf(m_r[q], mx);
      float ps = 0.f;
      #pragma unroll
      for (int j = 0; j < 4; ++j) {
        float p = __expf(p_v[j][q] - mnew);
        p_v[j][q] = p;
        ps += p;
      }
      #pragma unroll
      for (int o = 1; o < 16; o <<= 1) ps += __shfl_xor(ps, o);
      float alpha = __expf(m_r[q] - mnew);
      m_r[q] = mnew;
      l_r[q] = l_r[q] * alpha + ps;
      #pragma unroll
      for (int j = 0; j < 4; ++j) yacc[j][q] *= alpha;
      #pragma unroll
      for (int j = 0; j < 4; ++j) {
        int col = r16 + j * 16;
        Ps[qrow * 64 + (col ^ ((qrow & 7) << 3))] = (bf16)p_v[j][q];
      }
    }

    #pragma unroll
    for (int ks = 0; ks < 2; ++ks) {
      int prow = w16 + r16;
      bf16x8 pa = *reinterpret_cast<const bf16x8*>(&Ps[prow * 64 + (((g + 4 * ks) ^ (prow & 7)) * 8)]);
      #pragma unroll
      for (int j = 0; j < 4; ++j) {
        int vrow = j * 16 + r16;
        bf16x8 vb = *reinterpret_cast<const bf16x8*>(&Vs[vrow * 64 + (((g + 4 * ks) ^ (vrow & 7)) * 8)]);
        yacc[j] = __builtin_amdgcn_mfma_f32_16x16x32_bf16(pa, vb, yacc[j], 0, 0, 0);
      }
    }
  }

  #pragma unroll
  for (int q = 0; q < 4; ++q) {
    float inv = 1.0f / l_r[q];
    int tok = b * TDIM + qt * 64 + w16 + g * 4 + q;
    #pragma unroll
    for (int j = 0; j < 4; ++j)
      y[(size_t)tok * CDIM + h * 64 + r16 + j * 16] = (bf16)(yacc[j][q] * inv);
  }
}

// ---------------- launcher ----------------
extern "C" void kernel_launch(void* const* d_in, const int* in_sizes, int n_in,
                              void* d_out, int out_size, void* d_ws, size_t ws_size,
                              hipStream_t stream) {
  (void)in_sizes; (void)n_in; (void)out_size;
  const int*   idx    = (const int*)  d_in[0];
  const float* wte    = (const float*)d_in[1];
  const float* wpe    = (const float*)d_in[2];
  const float* ln1_s  = (const float*)d_in[3];
  const float* ln1_b  = (const float*)d_in[4];
  const float* qkv_w  = (const float*)d_in[5];
  const float* qkv_b  = (const float*)d_in[6];
  const float* proj_w = (const float*)d_in[7];
  const float* proj_b = (const float*)d_in[8];
  const float* ln2_s  = (const float*)d_in[9];
  const float* ln2_b  = (const float*)d_in[10];
  const float* fc_w   = (const float*)d_in[11];
  const float* fc_b   = (const float*)d_in[12];
  const float* fcp_w  = (const float*)d_in[13];
  const float* fcp_b  = (const float*)d_in[14];
  const float* lnf_s  = (const float*)d_in[15];
  const float* lnf_b  = (const float*)d_in[16];
  float* logits = (float*)d_out;

  char* base = (char*)d_ws;
  size_t off = 0;
  auto alloc = [&](size_t bytes) -> void* {
    void* p = base + off;
    off += (bytes + 255) & ~(size_t)255;
    return p;
  };
  bf16*  wte_bf  = (bf16*) alloc((size_t)VDIM * CDIM * 2);   // keep FIRST (logits B-tail overreads land in ws)
  bf16*  wq_all  = (bf16*) alloc((size_t)LNUM * 3 * CDIM * CDIM * 2);
  bf16*  wp_all  = (bf16*) alloc((size_t)LNUM * CDIM * CDIM * 2);
  bf16*  wf_all  = (bf16*) alloc((size_t)LNUM * 4 * CDIM * CDIM * 2);
  bf16*  wfp_all = (bf16*) alloc((size_t)LNUM * 4 * CDIM * CDIM * 2);
  float* x       = (float*)alloc((size_t)NTOK * CDIM * 4);
  bf16*  hb      = (bf16*) alloc((size_t)NTOK * CDIM * 2);
  bf16*  qkv_bf  = (bf16*) alloc((size_t)NTOK * 3 * CDIM * 2);
  bf16*  vt      = (bf16*) alloc((size_t)BDIM * HNUM * 64 * TDIM * 2);
  bf16*  yb      = (bf16*) alloc((size_t)NTOK * CDIM * 2);
  bf16*  gb      = (bf16*) alloc((size_t)NTOK * 4 * CDIM * 2);
  if (off > ws_size) return;

  k_cvt_bf16<<<4096, 256, 0, stream>>>(wte, wte_bf, (long)VDIM * CDIM);
  k_trans_all<<<LNUM * TILES_LAYER, 256, 0, stream>>>(qkv_w, proj_w, fc_w, fcp_w,
                                                      wq_all, wp_all, wf_all, wfp_all);
  k_embed<<<NTOK, 256, 0, stream>>>(idx, wte, wpe, x);

  for (int l = 0; l < LNUM; ++l) {
    const bf16* wq  = wq_all  + (size_t)l * 3 * CDIM * CDIM;
    const bf16* wp  = wp_all  + (size_t)l * CDIM * CDIM;
    const bf16* wf  = wf_all  + (size_t)l * 4 * CDIM * CDIM;
    const bf16* wfp = wfp_all + (size_t)l * 4 * CDIM * CDIM;

    k_layernorm<<<NTOK, 256, 0, stream>>>(x, ln1_s + l*CDIM, ln1_b + l*CDIM, hb);
    k_gemm8<4><<<16 * 9, 512, 0, stream>>>(hb, wq, qkv_b + (size_t)l*3*CDIM, nullptr, qkv_bf, 3*CDIM, CDIM);
    k_vtrans<<<dim3(BDIM*HNUM, TDIM/64), 256, 0, stream>>>(qkv_bf, vt);
    k_attn<<<dim3(BDIM*HNUM, TDIM/64), 256, 0, stream>>>(qkv_bf, vt, yb);
    k_gemm<64,4,2,2><<<dim3(NTOK/64, 6), 256, 0, stream>>>(yb, wp, proj_b + (size_t)l*CDIM, x, x, nullptr, NTOK, CDIM, CDIM);
    k_layernorm<<<NTOK, 256, 0, stream>>>(x, ln2_s + l*CDIM, ln2_b + l*CDIM, hb);
    k_gemm8<3><<<16 * 12, 512, 0, stream>>>(hb, wf, fc_b + (size_t)l*4*CDIM, nullptr, gb, 4*CDIM, CDIM);
    k_gemm<64,4,2,2><<<dim3(NTOK/64, 6), 256, 0, stream>>>(gb, wfp, fcp_b + (size_t)l*CDIM, x, x, nullptr, NTOK, CDIM, 4*CDIM);
  }

  k_layernorm<<<NTOK, 256, 0, stream>>>(x, lnf_s, lnf_b, hb);
  int ntile = (VDIM + 255) / 256;  // 197; tail masked in epilogue, staging overreads stay in ws
  k_gemm8<0><<<16 * ntile, 512, 0, stream>>>(hb, wte_bf, nullptr, logits, nullptr, VDIM, CDIM);
}

// Round 5
// 2276.740 us; speedup vs baseline: 1.0186x; 1.0186x over previous
//
#include <hip/hip_runtime.h>
#include <math.h>

#define LNUM 6
#define HNUM 12
#define CDIM 768
#define VDIM 50257
#define BDIM 4
#define TDIM 1024
#define NTOK 4096   // B*T

typedef __bf16 bf16;
typedef __bf16 bf16x8 __attribute__((ext_vector_type(8)));
typedef float  floatx4 __attribute__((ext_vector_type(4)));
typedef unsigned int u32;

// async global->LDS, 16B per lane. LDS dest must be wave-uniform base; HW adds lane*16.
__device__ inline void gload16(const bf16* gsrc, bf16* lds) {
  __builtin_amdgcn_global_load_lds(
      (const __attribute__((address_space(1))) u32*)gsrc,
      (__attribute__((address_space(3))) u32*)lds, 16, 0, 0);
}

// ---------------- fp32 -> bf16 bulk convert (wte) ----------------
__global__ void k_cvt_bf16(const float* __restrict__ in, bf16* __restrict__ out, long n) {
  long i = ((long)blockIdx.x * blockDim.x + threadIdx.x) * 4;
  long stride = (long)gridDim.x * blockDim.x * 4;
  for (; i < n; i += stride) {
    float4 v = *reinterpret_cast<const float4*>(in + i);
    bf16 b0 = (bf16)v.x, b1 = (bf16)v.y, b2 = (bf16)v.z, b3 = (bf16)v.w;
    ushort4 pk;
    pk.x = __builtin_bit_cast(unsigned short, b0);
    pk.y = __builtin_bit_cast(unsigned short, b1);
    pk.z = __builtin_bit_cast(unsigned short, b2);
    pk.w = __builtin_bit_cast(unsigned short, b3);
    *reinterpret_cast<ushort4*>(out + i) = pk;
  }
}

// -------- batched transpose+convert for ALL layer weights (one launch) --------
#define TILES_QKV  1728
#define TILES_PROJ 576
#define TILES_FC   2304
#define TILES_FCP  2304
#define TILES_LAYER (TILES_QKV + TILES_PROJ + TILES_FC + TILES_FCP)

__global__ __launch_bounds__(256) void k_trans_all(
    const float* __restrict__ qkv_w, const float* __restrict__ proj_w,
    const float* __restrict__ fc_w, const float* __restrict__ fcp_w,
    bf16* __restrict__ wq, bf16* __restrict__ wp,
    bf16* __restrict__ wf, bf16* __restrict__ wfp) {
  __shared__ float tile[32][33];
  int bid = blockIdx.x;
  int layer = bid / TILES_LAYER, r = bid % TILES_LAYER;
  const float* src; bf16* dst; int K, N, tx, ty;
  if (r < TILES_QKV) {
    src = qkv_w + (size_t)layer * CDIM * 3 * CDIM; dst = wq + (size_t)layer * CDIM * 3 * CDIM;
    K = CDIM; N = 3 * CDIM; tx = r % 72; ty = r / 72;
  } else if (r < TILES_QKV + TILES_PROJ) {
    r -= TILES_QKV;
    src = proj_w + (size_t)layer * CDIM * CDIM; dst = wp + (size_t)layer * CDIM * CDIM;
    K = CDIM; N = CDIM; tx = r % 24; ty = r / 24;
  } else if (r < TILES_QKV + TILES_PROJ + TILES_FC) {
    r -= TILES_QKV + TILES_PROJ;
    src = fc_w + (size_t)layer * CDIM * 4 * CDIM; dst = wf + (size_t)layer * CDIM * 4 * CDIM;
    K = CDIM; N = 4 * CDIM; tx = r % 96; ty = r / 96;
  } else {
    r -= TILES_QKV + TILES_PROJ + TILES_FC;
    src = fcp_w + (size_t)layer * 4 * CDIM * CDIM; dst = wfp + (size_t)layer * 4 * CDIM * CDIM;
    K = 4 * CDIM; N = CDIM; tx = r % 24; ty = r / 24;
  }
  int n0 = tx * 32, k0 = ty * 32;
  int nx = threadIdx.x & 31, tyy = threadIdx.x >> 5;
  #pragma unroll
  for (int p = 0; p < 4; ++p) {
    int k = tyy + p * 8;
    tile[k][nx] = src[(size_t)(k0 + k) * N + n0 + nx];
  }
  __syncthreads();
  #pragma unroll
  for (int p = 0; p < 4; ++p) {
    int n = tyy + p * 8;
    dst[(size_t)(n0 + n) * K + k0 + nx] = (bf16)tile[nx][n];
  }
}

// ---------------- embedding ----------------
__global__ void k_embed(const int* __restrict__ idx, const float* __restrict__ wte,
                        const float* __restrict__ wpe, float* __restrict__ x) {
  int tok = blockIdx.x;
  int t = tok & (TDIM - 1);
  int id = idx[tok];
  const float* a = wte + (size_t)id * CDIM;
  const float* p = wpe + (size_t)t * CDIM;
  float* o = x + (size_t)tok * CDIM;
  for (int c = threadIdx.x; c < CDIM; c += 256) o[c] = a[c] + p[c];
}

// ---------------- layernorm: fp32 in -> bf16 out ----------------
__global__ __launch_bounds__(256) void k_layernorm(const float* __restrict__ x,
    const float* __restrict__ sc, const float* __restrict__ bi, bf16* __restrict__ out) {
  __shared__ float red[8];
  int row = blockIdx.x;
  const float* xr = x + (size_t)row * CDIM;
  int t = threadIdx.x;
  float v0 = xr[t], v1 = xr[t + 256], v2 = xr[t + 512];
  float s = v0 + v1 + v2;
  #pragma unroll
  for (int o = 32; o > 0; o >>= 1) s += __shfl_down(s, o);
  if ((t & 63) == 0) red[t >> 6] = s;
  __syncthreads();
  float mean = (red[0] + red[1] + red[2] + red[3]) * (1.0f / CDIM);
  float d0 = v0 - mean, d1 = v1 - mean, d2 = v2 - mean;
  float q = d0 * d0 + d1 * d1 + d2 * d2;
  #pragma unroll
  for (int o = 32; o > 0; o >>= 1) q += __shfl_down(q, o);
  if ((t & 63) == 0) red[4 + (t >> 6)] = q;
  __syncthreads();
  float var = (red[4] + red[5] + red[6] + red[7]) * (1.0f / CDIM);
  float rs = rsqrtf(var + 1e-5f);
  bf16* orow = out + (size_t)row * CDIM;
  orow[t]       = (bf16)(d0 * rs * sc[t]       + bi[t]);
  orow[t + 256] = (bf16)(d1 * rs * sc[t + 256] + bi[t + 256]);
  orow[t + 512] = (bf16)(d2 * rs * sc[t + 512] + bi[t + 512]);
}

__device__ inline float gelu_f(float x) {
  float x3 = x * x * x;
  return 0.5f * x * (1.0f + tanhf(0.7978845608028654f * (x + 0.044715f * x3)));
}

// ================= 256x256 8-phase MFMA GEMM + L2-warming prefetch =================
// C[4096,N] = A[4096,K] * Bt[N,K]^T.  BM=BN=256, BK=64, 512 threads (8 waves, 2Mx4N).
// LDS: 2 buffers x 4 K-split regions {B@kk0, A@kk0, B@kk1, A@kk1}, each [256][32] bf16.
// Each phase: ds-read frags | stage 1 half (2 gload_lds) | PF 1 half 3 tiles ahead
// (2 gload_lds into dummy LDS, k clamped -> constant VMEM count) | bar | lgkm0 | 16 MFMA | bar.
// Tile-end wait vmcnt(14): newest-14 = ph0 PF(2) + ph1-3 (S2+P2)*3 -> everything through
// tile-t ph0's stages retired => all regions of tile t+1 provably landed. Tail: vmcnt(0).
// EPI: 0 ->f32 (no bias, N-tail guard), 3 +bias+gelu ->bf16, 4 +bias ->bf16
template<int EPI>
__global__ __launch_bounds__(512, 1) void k_gemm8(
    const bf16* __restrict__ A, const bf16* __restrict__ Bt,
    const float* __restrict__ bias,
    float* __restrict__ Cf, bf16* __restrict__ Cb,
    int N, int K) {
  __shared__ __align__(16) bf16 lds[2][4][8192];
  __shared__ __align__(16) bf16 pf_dummy[512];   // 1KB discard target for L2-warming loads
  const int nwg = gridDim.x;                      // divisible by 8
  const int id = blockIdx.x;
  const int swz = (id & 7) * (nwg >> 3) + (id >> 3);   // XCD-chunked (bijective, nwg%8==0)
  const int m0 = (swz & 15) * 256;
  const int n0 = (swz >> 4) * 256;
  const int tid = threadIdx.x, lane = tid & 63, wave = tid >> 6;
  const int wr = wave >> 2, wc = wave & 3;        // wave grid 2(M) x 4(N)
  const int g = lane >> 4, r16 = lane & 15;
  const int numK = K >> 6;
  const int wsl = wave * 512;

  const int srow = wave * 16 + (lane >> 2);
  const int scol = (lane & 3) * 8;
  const bf16* at  = A  + (size_t)(m0 + srow) * K + scol;
  const bf16* at1 = A  + (size_t)(m0 + srow + 128) * K + scol;
  const bf16* bt  = Bt + (size_t)(n0 + srow) * K + scol;
  const bf16* bt1 = Bt + (size_t)(n0 + srow + 128) * K + scol;
  const int a_off = (wr * 128 + r16) * 32 + g * 8;
  const int b_off = (wc * 64 + r16) * 32 + g * 8;

  floatx4 acc[8][4] = {};

#define G2(sA, sB, dst) do { gload16((sA), (dst)); gload16((sB), (dst) + 4096); } while (0)
#define PF2(pA, pB, off) do { gload16((pA) + (off), pf_dummy); gload16((pB) + (off), pf_dummy); } while (0)

  // prologue: tile0 full (H0-3) + 3 halves of tile1 (H4-6); no PFs -> vmcnt(6) exact
  G2(bt,      bt1,      &lds[0][0][wsl]);
  G2(at,      at1,      &lds[0][1][wsl]);
  G2(bt + 32, bt1 + 32, &lds[0][2][wsl]);
  G2(at + 32, at1 + 32, &lds[0][3][wsl]);
  G2(bt + 64, bt1 + 64, &lds[1][0][wsl]);
  G2(at + 64, at1 + 64, &lds[1][1][wsl]);
  G2(bt + 96, bt1 + 96, &lds[1][2][wsl]);
  asm volatile("s_waitcnt vmcnt(6)" ::: "memory");   // tile0's 8 loads landed
  __builtin_amdgcn_s_barrier();

  for (int t = 0; t < numK; ++t) {
    const int p = t & 1, pn = p ^ 1;
    // clamped prefetch offsets (relative to at/bt = col t*64): stage target + 3*64, <= K-64
    const int cmax = (K - 64) - (t << 6);          // >= 0 always
    const int p0 = cmax < 288 ? cmax : 288;        // mirrors ph0 stage (+96) + 192
    const int p1 = cmax < 320 ? cmax : 320;        // mirrors ph1/ph2 stage (+128) + 192
    const int p3 = cmax < 352 ? cmax : 352;        // mirrors ph3 stage (+160) + 192
    bf16x8 af[4], bfr[4];

    // ---- phase 0: kk=0, mgroup 0 ----
    #pragma unroll
    for (int j = 0; j < 4; ++j) bfr[j] = *(const bf16x8*)&lds[p][0][b_off + j * 512];
    #pragma unroll
    for (int i = 0; i < 4; ++i) af[i] = *(const bf16x8*)&lds[p][1][a_off + i * 512];
    if (t + 1 < numK) G2(at + 96, at1 + 96, &lds[pn][3][wsl]);
    PF2(at, at1, p0);
    __builtin_amdgcn_s_barrier();
    asm volatile("s_waitcnt lgkmcnt(0)" ::: "memory");
    __builtin_amdgcn_s_setprio(1);
    #pragma unroll
    for (int i = 0; i < 4; ++i)
      #pragma unroll
      for (int j = 0; j < 4; ++j)
        acc[i][j] = __builtin_amdgcn_mfma_f32_16x16x32_bf16(af[i], bfr[j], acc[i][j], 0, 0, 0);
    __builtin_amdgcn_s_setprio(0);
    __builtin_amdgcn_s_barrier();

    // ---- phase 1: kk=0, mgroup 1 (B regs reused) ----
    #pragma unroll
    for (int i = 0; i < 4; ++i) af[i] = *(const bf16x8*)&lds[p][1][a_off + (i + 4) * 512];
    if (t + 2 < numK) G2(bt + 128, bt1 + 128, &lds[p][0][wsl]);
    PF2(bt, bt1, p1);
    __builtin_amdgcn_s_barrier();
    asm volatile("s_waitcnt lgkmcnt(0)" ::: "memory");
    __builtin_amdgcn_s_setprio(1);
    #pragma unroll
    for (int i = 0; i < 4; ++i)
      #pragma unroll
      for (int j = 0; j < 4; ++j)
        acc[i + 4][j] = __builtin_amdgcn_mfma_f32_16x16x32_bf16(af[i], bfr[j], acc[i + 4][j], 0, 0, 0);
    __builtin_amdgcn_s_setprio(0);
    __builtin_amdgcn_s_barrier();

    // ---- phase 2: kk=1, mgroup 0 ----
    #pragma unroll
    for (int j = 0; j < 4; ++j) bfr[j] = *(const bf16x8*)&lds[p][2][b_off + j * 512];
    #pragma unroll
    for (int i = 0; i < 4; ++i) af[i] = *(const bf16x8*)&lds[p][3][a_off + i * 512];
    if (t + 2 < numK) G2(at + 128, at1 + 128, &lds[p][1][wsl]);
    PF2(at, at1, p1);
    __builtin_amdgcn_s_barrier();
    asm volatile("s_waitcnt lgkmcnt(0)" ::: "memory");
    __builtin_amdgcn_s_setprio(1);
    #pragma unroll
    for (int i = 0; i < 4; ++i)
      #pragma unroll
      for (int j = 0; j < 4; ++j)
        acc[i][j] = __builtin_amdgcn_mfma_f32_16x16x32_bf16(af[i], bfr[j], acc[i][j], 0, 0, 0);
    __builtin_amdgcn_s_setprio(0);
    __builtin_amdgcn_s_barrier();

    // ---- phase 3: kk=1, mgroup 1 (B regs reused) ----
    #pragma unroll
    for (int i = 0; i < 4; ++i) af[i] = *(const bf16x8*)&lds[p][3][a_off + (i + 4) * 512];
    if (t + 2 < numK) G2(bt + 160, bt1 + 160, &lds[p][2][wsl]);
    PF2(bt, bt1, p3);
    __builtin_amdgcn_s_barrier();
    asm volatile("s_waitcnt lgkmcnt(0)" ::: "memory");
    __builtin_amdgcn_s_setprio(1);
    #pragma unroll
    for (int i = 0; i < 4; ++i)
      #pragma unroll
      for (int j = 0; j < 4; ++j)
        acc[i + 4][j] = __builtin_amdgcn_mfma_f32_16x16x32_bf16(af[i], bfr[j], acc[i + 4][j], 0, 0, 0);
    __builtin_amdgcn_s_setprio(0);
    if (t + 2 < numK) { asm volatile("s_waitcnt vmcnt(14)" ::: "memory"); }
    else              { asm volatile("s_waitcnt vmcnt(0)" ::: "memory"); }
    __builtin_amdgcn_s_barrier();

    at += 64; at1 += 64; bt += 64; bt1 += 64;
  }
#undef G2
#undef PF2

  // ---------------- epilogue ----------------
  // C/D layout: col = lane&15, row = (lane>>4)*4 + reg
  if (EPI == 0) {
    const int mb = m0 + wr * 128 + g * 4;
    const int nb = n0 + wc * 64 + r16;
    #pragma unroll
    for (int nf = 0; nf < 4; ++nf) {
      int n = nb + nf * 16;
      if (n >= N) continue;
      #pragma unroll
      for (int mf = 0; mf < 8; ++mf) {
        #pragma unroll
        for (int q = 0; q < 4; ++q) {
          int m = mb + mf * 16 + q;
          Cf[(size_t)m * N + n] = acc[mf][nf][q];
        }
      }
    }
  } else {
    // wave-private LDS transpose -> 16B bf16x8 stores (full cache lines)
    bf16* sb = &lds[0][0][0] + wave * 1152;   // 16 rows x 72 stride
    const int rr_rd = lane & 15, seg = lane >> 4;
    const int nb = n0 + wc * 64 + r16;
    float bv[4];
    #pragma unroll
    for (int j = 0; j < 4; ++j) bv[j] = bias[nb + j * 16];
    #pragma unroll
    for (int mf = 0; mf < 8; ++mf) {
      #pragma unroll
      for (int j = 0; j < 4; ++j) {
        #pragma unroll
        for (int q = 0; q < 4; ++q) {
          float v = acc[mf][j][q] + bv[j];
          if (EPI == 3) v = gelu_f(v);
          sb[(g * 4 + q) * 72 + j * 16 + r16] = (bf16)v;
        }
      }
      bf16x8 o0 = *(const bf16x8*)&sb[rr_rd * 72 + seg * 16];
      bf16x8 o1 = *(const bf16x8*)&sb[rr_rd * 72 + seg * 16 + 8];
      size_t orow = (size_t)(m0 + wr * 128 + mf * 16 + rr_rd) * N + (n0 + wc * 64 + seg * 16);
      *(bf16x8*)&Cb[orow] = o0;
      *(bf16x8*)&Cb[orow + 8] = o1;
    }
  }
}

// ---------------- legacy 2-phase NT GEMM (proj / fcp: N=768) ----------------
template<int TBM, int MI, int NI, int EPI>
__global__ __launch_bounds__(256) void k_gemm(
    const bf16* __restrict__ A, const bf16* __restrict__ Bt,
    const float* __restrict__ bias, const float* __restrict__ resid,
    float* __restrict__ Cf, bf16* __restrict__ Cb,
    int M, int N, int K) {
  constexpr int BN = 128;
  constexpr int WGN = BN / (NI * 16);
  constexpr int AI = TBM / 32;
  constexpr int BI = BN / 32;
  __shared__ __align__(16) bf16 As[TBM * 64];
  __shared__ __align__(16) bf16 Bs[BN * 64];
  const int m0 = blockIdx.x * TBM, n0 = blockIdx.y * BN;
  const int tid = threadIdx.x;
  const int lane = tid & 63, wave = tid >> 6;
  const int wr = wave / WGN, wc = wave % WGN;
  const int l8 = lane >> 3, s8 = lane & 7;
  const int g = lane >> 4, r16 = lane & 15;

  floatx4 acc[MI][NI] = {};

  const bf16* a_src = A + (size_t)(m0 + l8) * K + s8 * 8;
  const bf16* b_src = Bt + (size_t)(n0 + l8) * K + s8 * 8;

  for (int k0 = 0; k0 < K; k0 += 64) {
    #pragma unroll
    for (int t = 0; t < AI; ++t) {
      int row0 = wave * (TBM / 4) + t * 8;
      gload16(a_src + (size_t)row0 * K + k0, &As[row0 * 64]);
    }
    #pragma unroll
    for (int t = 0; t < BI; ++t) {
      int row0 = wave * 32 + t * 8;
      gload16(b_src + (size_t)row0 * K + k0, &Bs[row0 * 64]);
    }
    __syncthreads();
    #pragma unroll
    for (int kk = 0; kk < 2; ++kk) {
      bf16x8 af[MI], bfr[NI];
      #pragma unroll
      for (int i = 0; i < MI; ++i)
        af[i] = *reinterpret_cast<const bf16x8*>(&As[(wr * MI * 16 + i * 16 + r16) * 64 + g * 8 + kk * 32]);
      #pragma unroll
      for (int j = 0; j < NI; ++j)
        bfr[j] = *reinterpret_cast<const bf16x8*>(&Bs[(wc * NI * 16 + j * 16 + r16) * 64 + g * 8 + kk * 32]);
      #pragma unroll
      for (int i = 0; i < MI; ++i) {
        #pragma unroll
        for (int j = 0; j < NI; ++j)
          acc[i][j] = __builtin_amdgcn_mfma_f32_16x16x32_bf16(af[i], bfr[j], acc[i][j], 0, 0, 0);
      }
    }
    __syncthreads();
  }

  int mb = m0 + wr * MI * 16 + g * 4;
  int nb = n0 + wc * NI * 16 + r16;
  #pragma unroll
  for (int j = 0; j < NI; ++j) {
    int n = nb + j * 16;
    if (n >= N) continue;
    float bv = (EPI >= 2) ? bias[n] : 0.0f;
    #pragma unroll
    for (int i = 0; i < MI; ++i) {
      #pragma unroll
      for (int q = 0; q < 4; ++q) {
        int m = mb + i * 16 + q;
        float v = acc[i][j][q] + bv;
        size_t o = (size_t)m * N + n;
        if (EPI == 2)      Cf[o] = v + resid[o];
        else if (EPI == 3) Cb[o] = (bf16)gelu_f(v);
        else if (EPI == 4) Cb[o] = (bf16)v;
        else               Cf[o] = v;
      }
    }
  }
}

// ---------------- V transpose: qkv_bf V-part -> vt[bh][d][t] bf16 ----------------
__global__ __launch_bounds__(256) void k_vtrans(const bf16* __restrict__ qkv, bf16* __restrict__ vt) {
  __shared__ bf16 tile[64][72];
  int bh = blockIdx.x, t0 = blockIdx.y * 64;
  int b = bh / HNUM, h = bh % HNUM;
  int tid = threadIdx.x;
  int r8 = tid >> 3, s8 = tid & 7;
  #pragma unroll
  for (int p = 0; p < 2; ++p) {
    int row = p * 32 + r8;
    uint4 v = *reinterpret_cast<const uint4*>(
        qkv + (size_t)(b * TDIM + t0 + row) * (3 * CDIM) + 2 * CDIM + h * 64 + s8 * 8);
    *reinterpret_cast<uint4*>(&tile[row][s8 * 8]) = v;
  }
  __syncthreads();
  int d = tid >> 2, q4 = tid & 3;
  #pragma unroll
  for (int half = 0; half < 2; ++half) {
    int t = q4 * 16 + half * 8;
    bf16x8 o;
    #pragma unroll
    for (int u = 0; u < 8; ++u) o[u] = tile[t + u][d];
    *reinterpret_cast<bf16x8*>(vt + (size_t)bh * (64 * TDIM) + (size_t)d * TDIM + t0 + t) = o;
  }
}

// ---------------- MFMA flash attention ----------------
__global__ __launch_bounds__(256) void k_attn(const bf16* __restrict__ qkv,
                                              const bf16* __restrict__ vt,
                                              bf16* __restrict__ y) {
  __shared__ __align__(16) bf16 Ks[64 * 64];
  __shared__ __align__(16) bf16 Vs[64 * 64];
  __shared__ __align__(16) bf16 Ps[64 * 64];
  const int bh = blockIdx.x, qt = blockIdx.y;
  const int b = bh / HNUM, h = bh % HNUM;
  const int tid = threadIdx.x, lane = tid & 63, wave = tid >> 6;
  const int g = lane >> 4, r16 = lane & 15;
  const int w16 = wave * 16;
  const int r8 = tid >> 3, s8 = tid & 7;

  bf16x8 qf[2];
  {
    const bf16* qsrc = qkv + (size_t)(b * TDIM + qt * 64 + w16 + r16) * (3 * CDIM) + h * 64 + g * 8;
    qf[0] = *reinterpret_cast<const bf16x8*>(qsrc);
    qf[1] = *reinterpret_cast<const bf16x8*>(qsrc + 32);
  }

  float m_r[4], l_r[4];
  floatx4 yacc[4] = {};
  #pragma unroll
  for (int q = 0; q < 4; ++q) { m_r[q] = -1e30f; l_r[q] = 0.f; }

  for (int kt = 0; kt <= qt; ++kt) {
    __syncthreads();
    #pragma unroll
    for (int p = 0; p < 2; ++p) {
      int row = p * 32 + r8;
      uint4 kv = *reinterpret_cast<const uint4*>(
          qkv + (size_t)(b * TDIM + kt * 64 + row) * (3 * CDIM) + CDIM + h * 64 + s8 * 8);
      *reinterpret_cast<uint4*>(&Ks[row * 64 + ((s8 ^ (row & 7)) * 8)]) = kv;
      uint4 vv = *reinterpret_cast<const uint4*>(
          vt + (size_t)bh * (64 * TDIM) + (size_t)row * TDIM + kt * 64 + s8 * 8);
      *reinterpret_cast<uint4*>(&Vs[row * 64 + ((s8 ^ (row & 7)) * 8)]) = vv;
    }
    __syncthreads();

    floatx4 sa[4] = {};
    #pragma unroll
    for (int c = 0; c < 2; ++c) {
      bf16x8 kf[4];
      #pragma unroll
      for (int j = 0; j < 4; ++j) {
        int krow = j * 16 + r16;
        kf[j] = *reinterpret_cast<const bf16x8*>(&Ks[krow * 64 + (((g + 4 * c) ^ (krow & 7)) * 8)]);
      }
      #pragma unroll
      for (int j = 0; j < 4; ++j)
        sa[j] = __builtin_amdgcn_mfma_f32_16x16x32_bf16(qf[c], kf[j], sa[j], 0, 0, 0);
    }

    const bool diag = (kt == qt);
    float p_v[4][4];
    #pragma unroll
    for (int q = 0; q < 4; ++q) {
      int qrow = w16 + g * 4 + q;
      float mx = -1e30f;
      #pragma unroll
      for (int j = 0; j < 4; ++j) {
        float s = sa[j][q] * 0.125f;
        if (diag && (r16 + j * 16) > qrow) s = -1e30f;
        p_v[j][q] = s;
        mx = fmaxf(mx, s);
      }
      #pragma unroll
      for (int o = 1; o < 16; o <<= 1) mx = fmaxf(mx, __shfl_xor(mx, o));
      float mnew = fmaxf(m_r[q], mx);
      float ps = 0.f;
      #pragma unroll
      for (int j = 0; j < 4; ++j) {
        float p = __expf(p_v[j][q] - mnew);
        p_v[j][q] = p;
        ps += p;
      }
      #pragma unroll
      for (int o = 1; o < 16; o <<= 1) ps += __shfl_xor(ps, o);
      float alpha = __expf(m_r[q] - mnew);
      m_r[q] = mnew;
      l_r[q] = l_r[q] * alpha + ps;
      #pragma unroll
      for (int j = 0; j < 4; ++j) yacc[j][q] *= alpha;
      #pragma unroll
      for (int j = 0; j < 4; ++j) {
        int col = r16 + j * 16;
        Ps[qrow * 64 + (col ^ ((qrow & 7) << 3))] = (bf16)p_v[j][q];
      }
    }

    #pragma unroll
    for (int ks = 0; ks < 2; ++ks) {
      int prow = w16 + r16;
      bf16x8 pa = *reinterpret_cast<const bf16x8*>(&Ps[prow * 64 + (((g + 4 * ks) ^ (prow & 7)) * 8)]);
      #pragma unroll
      for (int j = 0; j < 4; ++j) {
        int vrow = j * 16 + r16;
        bf16x8 vb = *reinterpret_cast<const bf16x8*>(&Vs[vrow * 64 + (((g + 4 * ks) ^ (vrow & 7)) * 8)]);
        yacc[j] = __builtin_amdgcn_mfma_f32_16x16x32_bf16(pa, vb, yacc[j], 0, 0, 0);
      }
    }
  }

  #pragma unroll
  for (int q = 0; q < 4; ++q) {
    float inv = 1.0f / l_r[q];
    int tok = b * TDIM + qt * 64 + w16 + g * 4 + q;
    #pragma unroll
    for (int j = 0; j < 4; ++j)
      y[(size_t)tok * CDIM + h * 64 + r16 + j * 16] = (bf16)(yacc[j][q] * inv);
  }
}

// ---------------- launcher ----------------
extern "C" void kernel_launch(void* const* d_in, const int* in_sizes, int n_in,
                              void* d_out, int out_size, void* d_ws, size_t ws_size,
                              hipStream_t stream) {
  (void)in_sizes; (void)n_in; (void)out_size;
  const int*   idx    = (const int*)  d_in[0];
  const float* wte    = (const float*)d_in[1];
  const float* wpe    = (const float*)d_in[2];
  const float* ln1_s  = (const float*)d_in[3];
  const float* ln1_b  = (const float*)d_in[4];
  const float* qkv_w  = (const float*)d_in[5];
  const float* qkv_b  = (const float*)d_in[6];
  const float* proj_w = (const float*)d_in[7];
  const float* proj_b = (const float*)d_in[8];
  const float* ln2_s  = (const float*)d_in[9];
  const float* ln2_b  = (const float*)d_in[10];
  const float* fc_w   = (const float*)d_in[11];
  const float* fc_b   = (const float*)d_in[12];
  const float* fcp_w  = (const float*)d_in[13];
  const float* fcp_b  = (const float*)d_in[14];
  const float* lnf_s  = (const float*)d_in[15];
  const float* lnf_b  = (const float*)d_in[16];
  float* logits = (float*)d_out;

  char* base = (char*)d_ws;
  size_t off = 0;
  auto alloc = [&](size_t bytes) -> void* {
    void* p = base + off;
    off += (bytes + 255) & ~(size_t)255;
    return p;
  };
  bf16*  wte_bf  = (bf16*) alloc((size_t)VDIM * CDIM * 2);   // keep FIRST (logits B-tail overreads land in ws)
  bf16*  wq_all  = (bf16*) alloc((size_t)LNUM * 3 * CDIM * CDIM * 2);
  bf16*  wp_all  = (bf16*) alloc((size_t)LNUM * CDIM * CDIM * 2);
  bf16*  wf_all  = (bf16*) alloc((size_t)LNUM * 4 * CDIM * CDIM * 2);
  bf16*  wfp_all = (bf16*) alloc((size_t)LNUM * 4 * CDIM * CDIM * 2);
  float* x       = (float*)alloc((size_t)NTOK * CDIM * 4);
  bf16*  hb      = (bf16*) alloc((size_t)NTOK * CDIM * 2);
  bf16*  qkv_bf  = (bf16*) alloc((size_t)NTOK * 3 * CDIM * 2);
  bf16*  vt      = (bf16*) alloc((size_t)BDIM * HNUM * 64 * TDIM * 2);
  bf16*  yb      = (bf16*) alloc((size_t)NTOK * CDIM * 2);
  bf16*  gb      = (bf16*) alloc((size_t)NTOK * 4 * CDIM * 2);
  if (off > ws_size) return;

  k_cvt_bf16<<<4096, 256, 0, stream>>>(wte, wte_bf, (long)VDIM * CDIM);
  k_trans_all<<<LNUM * TILES_LAYER, 256, 0, stream>>>(qkv_w, proj_w, fc_w, fcp_w,
                                                      wq_all, wp_all, wf_all, wfp_all);
  k_embed<<<NTOK, 256, 0, stream>>>(idx, wte, wpe, x);

  for (int l = 0; l < LNUM; ++l) {
    const bf16* wq  = wq_all  + (size_t)l * 3 * CDIM * CDIM;
    const bf16* wp  = wp_all  + (size_t)l * CDIM * CDIM;
    const bf16* wf  = wf_all  + (size_t)l * 4 * CDIM * CDIM;
    const bf16* wfp = wfp_all + (size_t)l * 4 * CDIM * CDIM;

    k_layernorm<<<NTOK, 256, 0, stream>>>(x, ln1_s + l*CDIM, ln1_b + l*CDIM, hb);
    k_gemm8<4><<<16 * 9, 512, 0, stream>>>(hb, wq, qkv_b + (size_t)l*3*CDIM, nullptr, qkv_bf, 3*CDIM, CDIM);
    k_vtrans<<<dim3(BDIM*HNUM, TDIM/64), 256, 0, stream>>>(qkv_bf, vt);
    k_attn<<<dim3(BDIM*HNUM, TDIM/64), 256, 0, stream>>>(qkv_bf, vt, yb);
    k_gemm<64,4,2,2><<<dim3(NTOK/64, 6), 256, 0, stream>>>(yb, wp, proj_b + (size_t)l*CDIM, x, x, nullptr, NTOK, CDIM, CDIM);
    k_layernorm<<<NTOK, 256, 0, stream>>>(x, ln2_s + l*CDIM, ln2_b + l*CDIM, hb);
    k_gemm8<3><<<16 * 12, 512, 0, stream>>>(hb, wf, fc_b + (size_t)l*4*CDIM, nullptr, gb, 4*CDIM, CDIM);
    k_gemm<64,4,2,2><<<dim3(NTOK/64, 6), 256, 0, stream>>>(gb, wfp, fcp_b + (size_t)l*CDIM, x, x, nullptr, NTOK, CDIM, 4*CDIM);
  }

  k_layernorm<<<NTOK, 256, 0, stream>>>(x, lnf_s, lnf_b, hb);
  int ntile = (VDIM + 255) / 256;  // 197; tail masked in epilogue, staging overreads stay in ws
  k_gemm8<0><<<16 * ntile, 512, 0, stream>>>(hb, wte_bf, nullptr, logits, nullptr, VDIM, CDIM);
}

// Round 6
// 1862.684 us; speedup vs baseline: 1.2450x; 1.2223x over previous
//
#include <hip/hip_runtime.h>
#include <math.h>

#define LNUM 6
#define HNUM 12
#define CDIM 768
#define VDIM 50257
#define BDIM 4
#define TDIM 1024
#define NTOK 4096   // B*T

typedef __bf16 bf16;
typedef __bf16 bf16x8 __attribute__((ext_vector_type(8)));
typedef float  floatx4 __attribute__((ext_vector_type(4)));
typedef unsigned int u32;

// async global->LDS, 16B per lane. LDS dest must be wave-uniform base; HW adds lane*16.
__device__ inline void gload16(const bf16* gsrc, bf16* lds) {
  __builtin_amdgcn_global_load_lds(
      (const __attribute__((address_space(1))) u32*)gsrc,
      (__attribute__((address_space(3))) u32*)lds, 16, 0, 0);
}

// ---------------- fp32 -> bf16 bulk convert (wte) ----------------
__global__ void k_cvt_bf16(const float* __restrict__ in, bf16* __restrict__ out, long n) {
  long i = ((long)blockIdx.x * blockDim.x + threadIdx.x) * 4;
  long stride = (long)gridDim.x * blockDim.x * 4;
  for (; i < n; i += stride) {
    float4 v = *reinterpret_cast<const float4*>(in + i);
    bf16 b0 = (bf16)v.x, b1 = (bf16)v.y, b2 = (bf16)v.z, b3 = (bf16)v.w;
    ushort4 pk;
    pk.x = __builtin_bit_cast(unsigned short, b0);
    pk.y = __builtin_bit_cast(unsigned short, b1);
    pk.z = __builtin_bit_cast(unsigned short, b2);
    pk.w = __builtin_bit_cast(unsigned short, b3);
    *reinterpret_cast<ushort4*>(out + i) = pk;
  }
}

// -------- batched transpose+convert for ALL layer weights (one launch) --------
#define TILES_QKV  1728
#define TILES_PROJ 576
#define TILES_FC   2304
#define TILES_FCP  2304
#define TILES_LAYER (TILES_QKV + TILES_PROJ + TILES_FC + TILES_FCP)

__global__ __launch_bounds__(256) void k_trans_all(
    const float* __restrict__ qkv_w, const float* __restrict__ proj_w,
    const float* __restrict__ fc_w, const float* __restrict__ fcp_w,
    bf16* __restrict__ wq, bf16* __restrict__ wp,
    bf16* __restrict__ wf, bf16* __restrict__ wfp) {
  __shared__ float tile[32][33];
  int bid = blockIdx.x;
  int layer = bid / TILES_LAYER, r = bid % TILES_LAYER;
  const float* src; bf16* dst; int K, N, tx, ty;
  if (r < TILES_QKV) {
    src = qkv_w + (size_t)layer * CDIM * 3 * CDIM; dst = wq + (size_t)layer * CDIM * 3 * CDIM;
    K = CDIM; N = 3 * CDIM; tx = r % 72; ty = r / 72;
  } else if (r < TILES_QKV + TILES_PROJ) {
    r -= TILES_QKV;
    src = proj_w + (size_t)layer * CDIM * CDIM; dst = wp + (size_t)layer * CDIM * CDIM;
    K = CDIM; N = CDIM; tx = r % 24; ty = r / 24;
  } else if (r < TILES_QKV + TILES_PROJ + TILES_FC) {
    r -= TILES_QKV + TILES_PROJ;
    src = fc_w + (size_t)layer * CDIM * 4 * CDIM; dst = wf + (size_t)layer * CDIM * 4 * CDIM;
    K = CDIM; N = 4 * CDIM; tx = r % 96; ty = r / 96;
  } else {
    r -= TILES_QKV + TILES_PROJ + TILES_FC;
    src = fcp_w + (size_t)layer * 4 * CDIM * CDIM; dst = wfp + (size_t)layer * 4 * CDIM * CDIM;
    K = 4 * CDIM; N = CDIM; tx = r % 24; ty = r / 24;
  }
  int n0 = tx * 32, k0 = ty * 32;
  int nx = threadIdx.x & 31, tyy = threadIdx.x >> 5;
  #pragma unroll
  for (int p = 0; p < 4; ++p) {
    int k = tyy + p * 8;
    tile[k][nx] = src[(size_t)(k0 + k) * N + n0 + nx];
  }
  __syncthreads();
  #pragma unroll
  for (int p = 0; p < 4; ++p) {
    int n = tyy + p * 8;
    dst[(size_t)(n0 + n) * K + k0 + nx] = (bf16)tile[nx][n];
  }
}

// ---------------- embedding ----------------
__global__ void k_embed(const int* __restrict__ idx, const float* __restrict__ wte,
                        const float* __restrict__ wpe, float* __restrict__ x) {
  int tok = blockIdx.x;
  int t = tok & (TDIM - 1);
  int id = idx[tok];
  const float* a = wte + (size_t)id * CDIM;
  const float* p = wpe + (size_t)t * CDIM;
  float* o = x + (size_t)tok * CDIM;
  for (int c = threadIdx.x; c < CDIM; c += 256) o[c] = a[c] + p[c];
}

// ---------------- layernorm: fp32 in -> bf16 out ----------------
__global__ __launch_bounds__(256) void k_layernorm(const float* __restrict__ x,
    const float* __restrict__ sc, const float* __restrict__ bi, bf16* __restrict__ out) {
  __shared__ float red[8];
  int row = blockIdx.x;
  const float* xr = x + (size_t)row * CDIM;
  int t = threadIdx.x;
  float v0 = xr[t], v1 = xr[t + 256], v2 = xr[t + 512];
  float s = v0 + v1 + v2;
  #pragma unroll
  for (int o = 32; o > 0; o >>= 1) s += __shfl_down(s, o);
  if ((t & 63) == 0) red[t >> 6] = s;
  __syncthreads();
  float mean = (red[0] + red[1] + red[2] + red[3]) * (1.0f / CDIM);
  float d0 = v0 - mean, d1 = v1 - mean, d2 = v2 - mean;
  float q = d0 * d0 + d1 * d1 + d2 * d2;
  #pragma unroll
  for (int o = 32; o > 0; o >>= 1) q += __shfl_down(q, o);
  if ((t & 63) == 0) red[4 + (t >> 6)] = q;
  __syncthreads();
  float var = (red[4] + red[5] + red[6] + red[7]) * (1.0f / CDIM);
  float rs = rsqrtf(var + 1e-5f);
  bf16* orow = out + (size_t)row * CDIM;
  orow[t]       = (bf16)(d0 * rs * sc[t]       + bi[t]);
  orow[t + 256] = (bf16)(d1 * rs * sc[t + 256] + bi[t + 256]);
  orow[t + 512] = (bf16)(d2 * rs * sc[t + 512] + bi[t + 512]);
}

__device__ inline float gelu_f(float x) {
  float x3 = x * x * x;
  return 0.5f * x * (1.0f + tanhf(0.7978845608028654f * (x + 0.044715f * x3)));
}

// ================= 256x256 8-phase MFMA GEMM (r3 schedule, new EPI0 epilogue) =================
// C[4096,N] = A[4096,K] * Bt[N,K]^T.  BM=BN=256, BK=64, 512 threads (8 waves, 2Mx4N).
// LDS: 2 buffers x 4 K-split regions {B@kk0, A@kk0, B@kk1, A@kk1}, each [256][32] bf16.
// Stage map (tile t): ph0: A+(t+1)*64+32 -> [t+1][3]; ph1: B+(t+2)*64 -> [t][0];
// ph2: A+(t+2)*64 -> [t][1]; ph3: B+(t+2)*64+32 -> [t][2].
// vmcnt(6) per tile end; vmcnt(0) when prefetch stops. numK >= 2.
// EPI: 0 ->f32 via LDS transpose + contiguous 16B stores (N-tail guarded),
//      3 +bias+gelu ->bf16, 4 +bias ->bf16
template<int EPI>
__global__ __launch_bounds__(512, 1) void k_gemm8(
    const bf16* __restrict__ A, const bf16* __restrict__ Bt,
    const float* __restrict__ bias,
    float* __restrict__ Cf, bf16* __restrict__ Cb,
    int N, int K) {
  __shared__ __align__(16) bf16 lds[2][4][8192];
  const int nwg = gridDim.x;                      // divisible by 8
  const int id = blockIdx.x;
  const int swz = (id & 7) * (nwg >> 3) + (id >> 3);   // XCD-chunked (bijective, nwg%8==0)
  const int m0 = (swz & 15) * 256;
  const int n0 = (swz >> 4) * 256;
  const int tid = threadIdx.x, lane = tid & 63, wave = tid >> 6;
  const int wr = wave >> 2, wc = wave & 3;        // wave grid 2(M) x 4(N)
  const int g = lane >> 4, r16 = lane & 15;
  const int numK = K >> 6;
  const int wsl = wave * 512;

  const int srow = wave * 16 + (lane >> 2);
  const int scol = (lane & 3) * 8;
  const bf16* at  = A  + (size_t)(m0 + srow) * K + scol;
  const bf16* at1 = A  + (size_t)(m0 + srow + 128) * K + scol;
  const bf16* bt  = Bt + (size_t)(n0 + srow) * K + scol;
  const bf16* bt1 = Bt + (size_t)(n0 + srow + 128) * K + scol;
  const int a_off = (wr * 128 + r16) * 32 + g * 8;
  const int b_off = (wc * 64 + r16) * 32 + g * 8;

  floatx4 acc[8][4] = {};

#define G2(sA, sB, dst) do { gload16((sA), (dst)); gload16((sB), (dst) + 4096); } while (0)

  // prologue: tile0 full (H0-3) + 3 halves of tile1 (H4-6)
  G2(bt,      bt1,      &lds[0][0][wsl]);
  G2(at,      at1,      &lds[0][1][wsl]);
  G2(bt + 32, bt1 + 32, &lds[0][2][wsl]);
  G2(at + 32, at1 + 32, &lds[0][3][wsl]);
  G2(bt + 64, bt1 + 64, &lds[1][0][wsl]);
  G2(at + 64, at1 + 64, &lds[1][1][wsl]);
  G2(bt + 96, bt1 + 96, &lds[1][2][wsl]);
  asm volatile("s_waitcnt vmcnt(6)" ::: "memory");   // tile0's 8 loads landed
  __builtin_amdgcn_s_barrier();

  for (int t = 0; t < numK; ++t) {
    const int p = t & 1, pn = p ^ 1;
    bf16x8 af[4], bfr[4];

    // ---- phase 0: kk=0, mgroup 0 ----
    #pragma unroll
    for (int j = 0; j < 4; ++j) bfr[j] = *(const bf16x8*)&lds[p][0][b_off + j * 512];
    #pragma unroll
    for (int i = 0; i < 4; ++i) af[i] = *(const bf16x8*)&lds[p][1][a_off + i * 512];
    if (t + 1 < numK) G2(at + 96, at1 + 96, &lds[pn][3][wsl]);
    __builtin_amdgcn_s_barrier();
    asm volatile("s_waitcnt lgkmcnt(0)" ::: "memory");
    __builtin_amdgcn_s_setprio(1);
    #pragma unroll
    for (int i = 0; i < 4; ++i)
      #pragma unroll
      for (int j = 0; j < 4; ++j)
        acc[i][j] = __builtin_amdgcn_mfma_f32_16x16x32_bf16(af[i], bfr[j], acc[i][j], 0, 0, 0);
    __builtin_amdgcn_s_setprio(0);
    __builtin_amdgcn_s_barrier();

    // ---- phase 1: kk=0, mgroup 1 (B regs reused) ----
    #pragma unroll
    for (int i = 0; i < 4; ++i) af[i] = *(const bf16x8*)&lds[p][1][a_off + (i + 4) * 512];
    if (t + 2 < numK) G2(bt + 128, bt1 + 128, &lds[p][0][wsl]);
    __builtin_amdgcn_s_barrier();
    asm volatile("s_waitcnt lgkmcnt(0)" ::: "memory");
    __builtin_amdgcn_s_setprio(1);
    #pragma unroll
    for (int i = 0; i < 4; ++i)
      #pragma unroll
      for (int j = 0; j < 4; ++j)
        acc[i + 4][j] = __builtin_amdgcn_mfma_f32_16x16x32_bf16(af[i], bfr[j], acc[i + 4][j], 0, 0, 0);
    __builtin_amdgcn_s_setprio(0);
    __builtin_amdgcn_s_barrier();

    // ---- phase 2: kk=1, mgroup 0 ----
    #pragma unroll
    for (int j = 0; j < 4; ++j) bfr[j] = *(const bf16x8*)&lds[p][2][b_off + j * 512];
    #pragma unroll
    for (int i = 0; i < 4; ++i) af[i] = *(const bf16x8*)&lds[p][3][a_off + i * 512];
    if (t + 2 < numK) G2(at + 128, at1 + 128, &lds[p][1][wsl]);
    __builtin_amdgcn_s_barrier();
    asm volatile("s_waitcnt lgkmcnt(0)" ::: "memory");
    __builtin_amdgcn_s_setprio(1);
    #pragma unroll
    for (int i = 0; i < 4; ++i)
      #pragma unroll
      for (int j = 0; j < 4; ++j)
        acc[i][j] = __builtin_amdgcn_mfma_f32_16x16x32_bf16(af[i], bfr[j], acc[i][j], 0, 0, 0);
    __builtin_amdgcn_s_setprio(0);
    __builtin_amdgcn_s_barrier();

    // ---- phase 3: kk=1, mgroup 1 (B regs reused) ----
    #pragma unroll
    for (int i = 0; i < 4; ++i) af[i] = *(const bf16x8*)&lds[p][3][a_off + (i + 4) * 512];
    if (t + 2 < numK) G2(bt + 160, bt1 + 160, &lds[p][2][wsl]);
    __builtin_amdgcn_s_barrier();
    asm volatile("s_waitcnt lgkmcnt(0)" ::: "memory");
    __builtin_amdgcn_s_setprio(1);
    #pragma unroll
    for (int i = 0; i < 4; ++i)
      #pragma unroll
      for (int j = 0; j < 4; ++j)
        acc[i + 4][j] = __builtin_amdgcn_mfma_f32_16x16x32_bf16(af[i], bfr[j], acc[i + 4][j], 0, 0, 0);
    __builtin_amdgcn_s_setprio(0);
    if (t + 2 < numK) { asm volatile("s_waitcnt vmcnt(6)" ::: "memory"); }
    else              { asm volatile("s_waitcnt vmcnt(0)" ::: "memory"); }
    __builtin_amdgcn_s_barrier();

    at += 64; at1 += 64; bt += 64; bt1 += 64;
  }
#undef G2

  // ---------------- epilogue ----------------
  // C/D layout: col = lane&15, row = (lane>>4)*4 + reg
  if (EPI == 0) {
    // wave-private LDS transpose (f32, stride 68) -> contiguous 16B row-segment stores
    float* sb = reinterpret_cast<float*>(&lds[0][0][0]) + wave * 1088;  // 16 rows x 68
    const int seg = lane & 15, rq = lane >> 4;
    const int mrow_base = m0 + wr * 128;
    const int ncol_base = n0 + wc * 64;
    #pragma unroll
    for (int mf = 0; mf < 8; ++mf) {
      #pragma unroll
      for (int nf = 0; nf < 4; ++nf) {
        #pragma unroll
        for (int q = 0; q < 4; ++q)
          sb[(g * 4 + q) * 68 + nf * 16 + r16] = acc[mf][nf][q];
      }
      #pragma unroll
      for (int pz = 0; pz < 4; ++pz) {
        int row = rq + pz * 4;                       // 0..15
        floatx4 v = *reinterpret_cast<const floatx4*>(&sb[row * 68 + seg * 4]);
        int m = mrow_base + mf * 16 + row;
        int n = ncol_base + seg * 4;
        if (n + 4 <= N) {
          __builtin_memcpy(&Cf[(size_t)m * N + n], &v, 16);   // 4B-aligned vector store
        } else {
          #pragma unroll
          for (int e = 0; e < 4; ++e)
            if (n + e < N) Cf[(size_t)m * N + n + e] = v[e];
        }
      }
    }
  } else {
    // wave-private LDS transpose -> 16B bf16x8 stores (full cache lines)
    bf16* sb = &lds[0][0][0] + wave * 1152;   // 16 rows x 72 stride
    const int rr_rd = lane & 15, seg = lane >> 4;
    const int nb = n0 + wc * 64 + r16;
    float bv[4];
    #pragma unroll
    for (int j = 0; j < 4; ++j) bv[j] = bias[nb + j * 16];
    #pragma unroll
    for (int mf = 0; mf < 8; ++mf) {
      #pragma unroll
      for (int j = 0; j < 4; ++j) {
        #pragma unroll
        for (int q = 0; q < 4; ++q) {
          float v = acc[mf][j][q] + bv[j];
          if (EPI == 3) v = gelu_f(v);
          sb[(g * 4 + q) * 72 + j * 16 + r16] = (bf16)v;
        }
      }
      bf16x8 o0 = *(const bf16x8*)&sb[rr_rd * 72 + seg * 16];
      bf16x8 o1 = *(const bf16x8*)&sb[rr_rd * 72 + seg * 16 + 8];
      size_t orow = (size_t)(m0 + wr * 128 + mf * 16 + rr_rd) * N + (n0 + wc * 64 + seg * 16);
      *(bf16x8*)&Cb[orow] = o0;
      *(bf16x8*)&Cb[orow + 8] = o1;
    }
  }
}

// ---------------- legacy 2-phase NT GEMM (proj / fcp: N=768) ----------------
template<int TBM, int MI, int NI, int EPI>
__global__ __launch_bounds__(256) void k_gemm(
    const bf16* __restrict__ A, const bf16* __restrict__ Bt,
    const float* __restrict__ bias, const float* __restrict__ resid,
    float* __restrict__ Cf, bf16* __restrict__ Cb,
    int M, int N, int K) {
  constexpr int BN = 128;
  constexpr int WGN = BN / (NI * 16);
  constexpr int AI = TBM / 32;
  constexpr int BI = BN / 32;
  __shared__ __align__(16) bf16 As[TBM * 64];
  __shared__ __align__(16) bf16 Bs[BN * 64];
  const int m0 = blockIdx.x * TBM, n0 = blockIdx.y * BN;
  const int tid = threadIdx.x;
  const int lane = tid & 63, wave = tid >> 6;
  const int wr = wave / WGN, wc = wave % WGN;
  const int l8 = lane >> 3, s8 = lane & 7;
  const int g = lane >> 4, r16 = lane & 15;

  floatx4 acc[MI][NI] = {};

  const bf16* a_src = A + (size_t)(m0 + l8) * K + s8 * 8;
  const bf16* b_src = Bt + (size_t)(n0 + l8) * K + s8 * 8;

  for (int k0 = 0; k0 < K; k0 += 64) {
    #pragma unroll
    for (int t = 0; t < AI; ++t) {
      int row0 = wave * (TBM / 4) + t * 8;
      gload16(a_src + (size_t)row0 * K + k0, &As[row0 * 64]);
    }
    #pragma unroll
    for (int t = 0; t < BI; ++t) {
      int row0 = wave * 32 + t * 8;
      gload16(b_src + (size_t)row0 * K + k0, &Bs[row0 * 64]);
    }
    __syncthreads();
    #pragma unroll
    for (int kk = 0; kk < 2; ++kk) {
      bf16x8 af[MI], bfr[NI];
      #pragma unroll
      for (int i = 0; i < MI; ++i)
        af[i] = *reinterpret_cast<const bf16x8*>(&As[(wr * MI * 16 + i * 16 + r16) * 64 + g * 8 + kk * 32]);
      #pragma unroll
      for (int j = 0; j < NI; ++j)
        bfr[j] = *reinterpret_cast<const bf16x8*>(&Bs[(wc * NI * 16 + j * 16 + r16) * 64 + g * 8 + kk * 32]);
      #pragma unroll
      for (int i = 0; i < MI; ++i) {
        #pragma unroll
        for (int j = 0; j < NI; ++j)
          acc[i][j] = __builtin_amdgcn_mfma_f32_16x16x32_bf16(af[i], bfr[j], acc[i][j], 0, 0, 0);
      }
    }
    __syncthreads();
  }

  int mb = m0 + wr * MI * 16 + g * 4;
  int nb = n0 + wc * NI * 16 + r16;
  #pragma unroll
  for (int j = 0; j < NI; ++j) {
    int n = nb + j * 16;
    if (n >= N) continue;
    float bv = (EPI >= 2) ? bias[n] : 0.0f;
    #pragma unroll
    for (int i = 0; i < MI; ++i) {
      #pragma unroll
      for (int q = 0; q < 4; ++q) {
        int m = mb + i * 16 + q;
        float v = acc[i][j][q] + bv;
        size_t o = (size_t)m * N + n;
        if (EPI == 2)      Cf[o] = v + resid[o];
        else if (EPI == 3) Cb[o] = (bf16)gelu_f(v);
        else if (EPI == 4) Cb[o] = (bf16)v;
        else               Cf[o] = v;
      }
    }
  }
}

// ---------------- V transpose: qkv_bf V-part -> vt[bh][d][t] bf16 ----------------
__global__ __launch_bounds__(256) void k_vtrans(const bf16* __restrict__ qkv, bf16* __restrict__ vt) {
  __shared__ bf16 tile[64][72];
  int bh = blockIdx.x, t0 = blockIdx.y * 64;
  int b = bh / HNUM, h = bh % HNUM;
  int tid = threadIdx.x;
  int r8 = tid >> 3, s8 = tid & 7;
  #pragma unroll
  for (int p = 0; p < 2; ++p) {
    int row = p * 32 + r8;
    uint4 v = *reinterpret_cast<const uint4*>(
        qkv + (size_t)(b * TDIM + t0 + row) * (3 * CDIM) + 2 * CDIM + h * 64 + s8 * 8);
    *reinterpret_cast<uint4*>(&tile[row][s8 * 8]) = v;
  }
  __syncthreads();
  int d = tid >> 2, q4 = tid & 3;
  #pragma unroll
  for (int half = 0; half < 2; ++half) {
    int t = q4 * 16 + half * 8;
    bf16x8 o;
    #pragma unroll
    for (int u = 0; u < 8; ++u) o[u] = tile[t + u][d];
    *reinterpret_cast<bf16x8*>(vt + (size_t)bh * (64 * TDIM) + (size_t)d * TDIM + t0 + t) = o;
  }
}

// ---------------- MFMA flash attention ----------------
__global__ __launch_bounds__(256) void k_attn(const bf16* __restrict__ qkv,
                                              const bf16* __restrict__ vt,
                                              bf16* __restrict__ y) {
  __shared__ __align__(16) bf16 Ks[64 * 64];
  __shared__ __align__(16) bf16 Vs[64 * 64];
  __shared__ __align__(16) bf16 Ps[64 * 64];
  const int bh = blockIdx.x, qt = blockIdx.y;
  const int b = bh / HNUM, h = bh % HNUM;
  const int tid = threadIdx.x, lane = tid & 63, wave = tid >> 6;
  const int g = lane >> 4, r16 = lane & 15;
  const int w16 = wave * 16;
  const int r8 = tid >> 3, s8 = tid & 7;

  bf16x8 qf[2];
  {
    const bf16* qsrc = qkv + (size_t)(b * TDIM + qt * 64 + w16 + r16) * (3 * CDIM) + h * 64 + g * 8;
    qf[0] = *reinterpret_cast<const bf16x8*>(qsrc);
    qf[1] = *reinterpret_cast<const bf16x8*>(qsrc + 32);
  }

  float m_r[4], l_r[4];
  floatx4 yacc[4] = {};
  #pragma unroll
  for (int q = 0; q < 4; ++q) { m_r[q] = -1e30f; l_r[q] = 0.f; }

  for (int kt = 0; kt <= qt; ++kt) {
    __syncthreads();
    #pragma unroll
    for (int p = 0; p < 2; ++p) {
      int row = p * 32 + r8;
      uint4 kv = *reinterpret_cast<const uint4*>(
          qkv + (size_t)(b * TDIM + kt * 64 + row) * (3 * CDIM) + CDIM + h * 64 + s8 * 8);
      *reinterpret_cast<uint4*>(&Ks[row * 64 + ((s8 ^ (row & 7)) * 8)]) = kv;
      uint4 vv = *reinterpret_cast<const uint4*>(
          vt + (size_t)bh * (64 * TDIM) + (size_t)row * TDIM + kt * 64 + s8 * 8);
      *reinterpret_cast<uint4*>(&Vs[row * 64 + ((s8 ^ (row & 7)) * 8)]) = vv;
    }
    __syncthreads();

    floatx4 sa[4] = {};
    #pragma unroll
    for (int c = 0; c < 2; ++c) {
      bf16x8 kf[4];
      #pragma unroll
      for (int j = 0; j < 4; ++j) {
        int krow = j * 16 + r16;
        kf[j] = *reinterpret_cast<const bf16x8*>(&Ks[krow * 64 + (((g + 4 * c) ^ (krow & 7)) * 8)]);
      }
      #pragma unroll
      for (int j = 0; j < 4; ++j)
        sa[j] = __builtin_amdgcn_mfma_f32_16x16x32_bf16(qf[c], kf[j], sa[j], 0, 0, 0);
    }

    const bool diag = (kt == qt);
    float p_v[4][4];
    #pragma unroll
    for (int q = 0; q < 4; ++q) {
      int qrow = w16 + g * 4 + q;
      float mx = -1e30f;
      #pragma unroll
      for (int j = 0; j < 4; ++j) {
        float s = sa[j][q] * 0.125f;
        if (diag && (r16 + j * 16) > qrow) s = -1e30f;
        p_v[j][q] = s;
        mx = fmaxf(mx, s);
      }
      #pragma unroll
      for (int o = 1; o < 16; o <<= 1) mx = fmaxf(mx, __shfl_xor(mx, o));
      float mnew = fmaxf(m_r[q], mx);
      float ps = 0.f;
      #pragma unroll
      for (int j = 0; j < 4; ++j) {
        float p = __expf(p_v[j][q] - mnew);
        p_v[j][q] = p;
        ps += p;
      }
      #pragma unroll
      for (int o = 1; o < 16; o <<= 1) ps += __shfl_xor(ps, o);
      float alpha = __expf(m_r[q] - mnew);
      m_r[q] = mnew;
      l_r[q] = l_r[q] * alpha + ps;
      #pragma unroll
      for (int j = 0; j < 4; ++j) yacc[j][q] *= alpha;
      #pragma unroll
      for (int j = 0; j < 4; ++j) {
        int col = r16 + j * 16;
        Ps[qrow * 64 + (col ^ ((qrow & 7) << 3))] = (bf16)p_v[j][q];
      }
    }

    #pragma unroll
    for (int ks = 0; ks < 2; ++ks) {
      int prow = w16 + r16;
      bf16x8 pa = *reinterpret_cast<const bf16x8*>(&Ps[prow * 64 + (((g + 4 * ks) ^ (prow & 7)) * 8)]);
      #pragma unroll
      for (int j = 0; j < 4; ++j) {
        int vrow = j * 16 + r16;
        bf16x8 vb = *reinterpret_cast<const bf16x8*>(&Vs[vrow * 64 + (((g + 4 * ks) ^ (vrow & 7)) * 8)]);
        yacc[j] = __builtin_amdgcn_mfma_f32_16x16x32_bf16(pa, vb, yacc[j], 0, 0, 0);
      }
    }
  }

  #pragma unroll
  for (int q = 0; q < 4; ++q) {
    float inv = 1.0f / l_r[q];
    int tok = b * TDIM + qt * 64 + w16 + g * 4 + q;
    #pragma unroll
    for (int j = 0; j < 4; ++j)
      y[(size_t)tok * CDIM + h * 64 + r16 + j * 16] = (bf16)(yacc[j][q] * inv);
  }
}

// ---------------- launcher ----------------
extern "C" void kernel_launch(void* const* d_in, const int* in_sizes, int n_in,
                              void* d_out, int out_size, void* d_ws, size_t ws_size,
                              hipStream_t stream) {
  (void)in_sizes; (void)n_in; (void)out_size;
  const int*   idx    = (const int*)  d_in[0];
  const float* wte    = (const float*)d_in[1];
  const float* wpe    = (const float*)d_in[2];
  const float* ln1_s  = (const float*)d_in[3];
  const float* ln1_b  = (const float*)d_in[4];
  const float* qkv_w  = (const float*)d_in[5];
  const float* qkv_b  = (const float*)d_in[6];
  const float* proj_w = (const float*)d_in[7];
  const float* proj_b = (const float*)d_in[8];
  const float* ln2_s  = (const float*)d_in[9];
  const float* ln2_b  = (const float*)d_in[10];
  const float* fc_w   = (const float*)d_in[11];
  const float* fc_b   = (const float*)d_in[12];
  const float* fcp_w  = (const float*)d_in[13];
  const float* fcp_b  = (const float*)d_in[14];
  const float* lnf_s  = (const float*)d_in[15];
  const float* lnf_b  = (const float*)d_in[16];
  float* logits = (float*)d_out;

  char* base = (char*)d_ws;
  size_t off = 0;
  auto alloc = [&](size_t bytes) -> void* {
    void* p = base + off;
    off += (bytes + 255) & ~(size_t)255;
    return p;
  };
  bf16*  wte_bf  = (bf16*) alloc((size_t)VDIM * CDIM * 2);   // keep FIRST (logits B-tail overreads land in ws)
  bf16*  wq_all  = (bf16*) alloc((size_t)LNUM * 3 * CDIM * CDIM * 2);
  bf16*  wp_all  = (bf16*) alloc((size_t)LNUM * CDIM * CDIM * 2);
  bf16*  wf_all  = (bf16*) alloc((size_t)LNUM * 4 * CDIM * CDIM * 2);
  bf16*  wfp_all = (bf16*) alloc((size_t)LNUM * 4 * CDIM * CDIM * 2);
  float* x       = (float*)alloc((size_t)NTOK * CDIM * 4);
  bf16*  hb      = (bf16*) alloc((size_t)NTOK * CDIM * 2);
  bf16*  qkv_bf  = (bf16*) alloc((size_t)NTOK * 3 * CDIM * 2);
  bf16*  vt      = (bf16*) alloc((size_t)BDIM * HNUM * 64 * TDIM * 2);
  bf16*  yb      = (bf16*) alloc((size_t)NTOK * CDIM * 2);
  bf16*  gb      = (bf16*) alloc((size_t)NTOK * 4 * CDIM * 2);
  if (off > ws_size) return;

  k_cvt_bf16<<<4096, 256, 0, stream>>>(wte, wte_bf, (long)VDIM * CDIM);
  k_trans_all<<<LNUM * TILES_LAYER, 256, 0, stream>>>(qkv_w, proj_w, fc_w, fcp_w,
                                                      wq_all, wp_all, wf_all, wfp_all);
  k_embed<<<NTOK, 256, 0, stream>>>(idx, wte, wpe, x);

  for (int l = 0; l < LNUM; ++l) {
    const bf16* wq  = wq_all  + (size_t)l * 3 * CDIM * CDIM;
    const bf16* wp  = wp_all  + (size_t)l * CDIM * CDIM;
    const bf16* wf  = wf_all  + (size_t)l * 4 * CDIM * CDIM;
    const bf16* wfp = wfp_all + (size_t)l * 4 * CDIM * CDIM;

    k_layernorm<<<NTOK, 256, 0, stream>>>(x, ln1_s + l*CDIM, ln1_b + l*CDIM, hb);
    k_gemm8<4><<<16 * 9, 512, 0, stream>>>(hb, wq, qkv_b + (size_t)l*3*CDIM, nullptr, qkv_bf, 3*CDIM, CDIM);
    k_vtrans<<<dim3(BDIM*HNUM, TDIM/64), 256, 0, stream>>>(qkv_bf, vt);
    k_attn<<<dim3(BDIM*HNUM, TDIM/64), 256, 0, stream>>>(qkv_bf, vt, yb);
    k_gemm<64,4,2,2><<<dim3(NTOK/64, 6), 256, 0, stream>>>(yb, wp, proj_b + (size_t)l*CDIM, x, x, nullptr, NTOK, CDIM, CDIM);
    k_layernorm<<<NTOK, 256, 0, stream>>>(x, ln2_s + l*CDIM, ln2_b + l*CDIM, hb);
    k_gemm8<3><<<16 * 12, 512, 0, stream>>>(hb, wf, fc_b + (size_t)l*4*CDIM, nullptr, gb, 4*CDIM, CDIM);
    k_gemm<64,4,2,2><<<dim3(NTOK/64, 6), 256, 0, stream>>>(gb, wfp, fcp_b + (size_t)l*CDIM, x, x, nullptr, NTOK, CDIM, 4*CDIM);
  }

  k_layernorm<<<NTOK, 256, 0, stream>>>(x, lnf_s, lnf_b, hb);
  int ntile = (VDIM + 255) / 256;  // 197; tail masked in epilogue, staging overreads stay in ws
  k_gemm8<0><<<16 * ntile, 512, 0, stream>>>(hb, wte_bf, nullptr, logits, nullptr, VDIM, CDIM);
}

// Round 7
// 1839.332 us; speedup vs baseline: 1.2608x; 1.0127x over previous
//
#include <hip/hip_runtime.h>
#include <math.h>

#define LNUM 6
#define HNUM 12
#define CDIM 768
#define VDIM 50257
#define BDIM 4
#define TDIM 1024
#define NTOK 4096   // B*T

typedef __bf16 bf16;
typedef __bf16 bf16x8 __attribute__((ext_vector_type(8)));
typedef float  floatx4 __attribute__((ext_vector_type(4)));
typedef unsigned int u32;

// async global->LDS, 16B per lane. LDS dest must be wave-uniform base; HW adds lane*16.
__device__ inline void gload16(const bf16* gsrc, bf16* lds) {
  __builtin_amdgcn_global_load_lds(
      (const __attribute__((address_space(1))) u32*)gsrc,
      (__attribute__((address_space(3))) u32*)lds, 16, 0, 0);
}

// ---------------- fp32 -> bf16 bulk convert (wte) ----------------
__global__ void k_cvt_bf16(const float* __restrict__ in, bf16* __restrict__ out, long n) {
  long i = ((long)blockIdx.x * blockDim.x + threadIdx.x) * 4;
  long stride = (long)gridDim.x * blockDim.x * 4;
  for (; i < n; i += stride) {
    float4 v = *reinterpret_cast<const float4*>(in + i);
    bf16 b0 = (bf16)v.x, b1 = (bf16)v.y, b2 = (bf16)v.z, b3 = (bf16)v.w;
    ushort4 pk;
    pk.x = __builtin_bit_cast(unsigned short, b0);
    pk.y = __builtin_bit_cast(unsigned short, b1);
    pk.z = __builtin_bit_cast(unsigned short, b2);
    pk.w = __builtin_bit_cast(unsigned short, b3);
    *reinterpret_cast<ushort4*>(out + i) = pk;
  }
}

// -------- batched transpose+convert for ALL layer weights (one launch) --------
#define TILES_QKV  1728
#define TILES_PROJ 576
#define TILES_FC   2304
#define TILES_FCP  2304
#define TILES_LAYER (TILES_QKV + TILES_PROJ + TILES_FC + TILES_FCP)

__global__ __launch_bounds__(256) void k_trans_all(
    const float* __restrict__ qkv_w, const float* __restrict__ proj_w,
    const float* __restrict__ fc_w, const float* __restrict__ fcp_w,
    bf16* __restrict__ wq, bf16* __restrict__ wp,
    bf16* __restrict__ wf, bf16* __restrict__ wfp) {
  __shared__ float tile[32][33];
  int bid = blockIdx.x;
  int layer = bid / TILES_LAYER, r = bid % TILES_LAYER;
  const float* src; bf16* dst; int K, N, tx, ty;
  if (r < TILES_QKV) {
    src = qkv_w + (size_t)layer * CDIM * 3 * CDIM; dst = wq + (size_t)layer * CDIM * 3 * CDIM;
    K = CDIM; N = 3 * CDIM; tx = r % 72; ty = r / 72;
  } else if (r < TILES_QKV + TILES_PROJ) {
    r -= TILES_QKV;
    src = proj_w + (size_t)layer * CDIM * CDIM; dst = wp + (size_t)layer * CDIM * CDIM;
    K = CDIM; N = CDIM; tx = r % 24; ty = r / 24;
  } else if (r < TILES_QKV + TILES_PROJ + TILES_FC) {
    r -= TILES_QKV + TILES_PROJ;
    src = fc_w + (size_t)layer * CDIM * 4 * CDIM; dst = wf + (size_t)layer * CDIM * 4 * CDIM;
    K = CDIM; N = 4 * CDIM; tx = r % 96; ty = r / 96;
  } else {
    r -= TILES_QKV + TILES_PROJ + TILES_FC;
    src = fcp_w + (size_t)layer * 4 * CDIM * CDIM; dst = wfp + (size_t)layer * 4 * CDIM * CDIM;
    K = 4 * CDIM; N = CDIM; tx = r % 24; ty = r / 24;
  }
  int n0 = tx * 32, k0 = ty * 32;
  int nx = threadIdx.x & 31, tyy = threadIdx.x >> 5;
  #pragma unroll
  for (int p = 0; p < 4; ++p) {
    int k = tyy + p * 8;
    tile[k][nx] = src[(size_t)(k0 + k) * N + n0 + nx];
  }
  __syncthreads();
  #pragma unroll
  for (int p = 0; p < 4; ++p) {
    int n = tyy + p * 8;
    dst[(size_t)(n0 + n) * K + k0 + nx] = (bf16)tile[nx][n];
  }
}

// ---------------- embedding ----------------
__global__ void k_embed(const int* __restrict__ idx, const float* __restrict__ wte,
                        const float* __restrict__ wpe, float* __restrict__ x) {
  int tok = blockIdx.x;
  int t = tok & (TDIM - 1);
  int id = idx[tok];
  const float* a = wte + (size_t)id * CDIM;
  const float* p = wpe + (size_t)t * CDIM;
  float* o = x + (size_t)tok * CDIM;
  for (int c = threadIdx.x; c < CDIM; c += 256) o[c] = a[c] + p[c];
}

// ---------------- layernorm: fp32 in -> bf16 out ----------------
__global__ __launch_bounds__(256) void k_layernorm(const float* __restrict__ x,
    const float* __restrict__ sc, const float* __restrict__ bi, bf16* __restrict__ out) {
  __shared__ float red[8];
  int row = blockIdx.x;
  const float* xr = x + (size_t)row * CDIM;
  int t = threadIdx.x;
  float v0 = xr[t], v1 = xr[t + 256], v2 = xr[t + 512];
  float s = v0 + v1 + v2;
  #pragma unroll
  for (int o = 32; o > 0; o >>= 1) s += __shfl_down(s, o);
  if ((t & 63) == 0) red[t >> 6] = s;
  __syncthreads();
  float mean = (red[0] + red[1] + red[2] + red[3]) * (1.0f / CDIM);
  float d0 = v0 - mean, d1 = v1 - mean, d2 = v2 - mean;
  float q = d0 * d0 + d1 * d1 + d2 * d2;
  #pragma unroll
  for (int o = 32; o > 0; o >>= 1) q += __shfl_down(q, o);
  if ((t & 63) == 0) red[4 + (t >> 6)] = q;
  __syncthreads();
  float var = (red[4] + red[5] + red[6] + red[7]) * (1.0f / CDIM);
  float rs = rsqrtf(var + 1e-5f);
  bf16* orow = out + (size_t)row * CDIM;
  orow[t]       = (bf16)(d0 * rs * sc[t]       + bi[t]);
  orow[t + 256] = (bf16)(d1 * rs * sc[t + 256] + bi[t + 256]);
  orow[t + 512] = (bf16)(d2 * rs * sc[t + 512] + bi[t + 512]);
}

__device__ inline float gelu_f(float x) {
  float x3 = x * x * x;
  return 0.5f * x * (1.0f + tanhf(0.7978845608028654f * (x + 0.044715f * x3)));
}

// ================= 256x256 8-phase MFMA GEMM (T2-swizzled LDS) =================
// C[4096,N] = A[4096,K] * Bt[N,K]^T.  BM=BN=256, BK=64, 512 threads (8 waves, 2Mx4N).
// LDS: 2 buffers x 4 K-split regions {B@kk0, A@kk0, B@kk1, A@kk1}, each [256 rows][4 slots of 16B].
// T2 swizzle (rule 21: gload_lds writes linearly -> inverse-permute the GLOBAL SOURCE column,
// apply the same XOR on the read): LDS[row][s] holds global slot s ^ ((row>>1)&3).
// Read granule = (4*(r16&1) + g^((r16>>1)&3)) mod 8 -> all 8 distinct per 16-lane group,
// full wave touches 64 distinct 16B granules = LDS floor (was 8-way conflict).
// Stage map (tile t): ph0: A+(t+1)*64+32 -> [t+1][3]; ph1: B+(t+2)*64 -> [t][0];
// ph2: A+(t+2)*64 -> [t][1]; ph3: B+(t+2)*64+32 -> [t][2].
// vmcnt(6) per tile end; vmcnt(0) when prefetch stops. numK >= 2.
// EPI: 0 ->f32 via LDS transpose + contiguous 16B stores (N-tail guarded),
//      3 +bias+gelu ->bf16, 4 +bias ->bf16
template<int EPI>
__global__ __launch_bounds__(512, 1) void k_gemm8(
    const bf16* __restrict__ A, const bf16* __restrict__ Bt,
    const float* __restrict__ bias,
    float* __restrict__ Cf, bf16* __restrict__ Cb,
    int N, int K) {
  __shared__ __align__(16) bf16 lds[2][4][8192];
  const int nwg = gridDim.x;                      // divisible by 8
  const int id = blockIdx.x;
  const int swz = (id & 7) * (nwg >> 3) + (id >> 3);   // XCD-chunked (bijective, nwg%8==0)
  const int m0 = (swz & 15) * 256;
  const int n0 = (swz >> 4) * 256;
  const int tid = threadIdx.x, lane = tid & 63, wave = tid >> 6;
  const int wr = wave >> 2, wc = wave & 3;        // wave grid 2(M) x 4(N)
  const int g = lane >> 4, r16 = lane & 15;
  const int numK = K >> 6;
  const int wsl = wave * 512;

  const int srow = wave * 16 + (lane >> 2);
  // T2: source column permuted so linear LDS dest ends up swizzled
  const int scol = ((lane & 3) ^ ((lane >> 3) & 3)) * 8;
  const bf16* at  = A  + (size_t)(m0 + srow) * K + scol;
  const bf16* at1 = A  + (size_t)(m0 + srow + 128) * K + scol;
  const bf16* bt  = Bt + (size_t)(n0 + srow) * K + scol;
  const bf16* bt1 = Bt + (size_t)(n0 + srow + 128) * K + scol;
  // T2: read with the same XOR; term uniform per lane (all row bases == 0 mod 32)
  const int sw = (g ^ ((r16 >> 1) & 3)) * 8;
  const int a_off = (wr * 128 + r16) * 32 + sw;
  const int b_off = (wc * 64 + r16) * 32 + sw;

  floatx4 acc[8][4] = {};

#define G2(sA, sB, dst) do { gload16((sA), (dst)); gload16((sB), (dst) + 4096); } while (0)

  // prologue: tile0 full (H0-3) + 3 halves of tile1 (H4-6)
  G2(bt,      bt1,      &lds[0][0][wsl]);
  G2(at,      at1,      &lds[0][1][wsl]);
  G2(bt + 32, bt1 + 32, &lds[0][2][wsl]);
  G2(at + 32, at1 + 32, &lds[0][3][wsl]);
  G2(bt + 64, bt1 + 64, &lds[1][0][wsl]);
  G2(at + 64, at1 + 64, &lds[1][1][wsl]);
  G2(bt + 96, bt1 + 96, &lds[1][2][wsl]);
  asm volatile("s_waitcnt vmcnt(6)" ::: "memory");   // tile0's 8 loads landed
  __builtin_amdgcn_s_barrier();

  for (int t = 0; t < numK; ++t) {
    const int p = t & 1, pn = p ^ 1;
    bf16x8 af[4], bfr[4];

    // ---- phase 0: kk=0, mgroup 0 ----
    #pragma unroll
    for (int j = 0; j < 4; ++j) bfr[j] = *(const bf16x8*)&lds[p][0][b_off + j * 512];
    #pragma unroll
    for (int i = 0; i < 4; ++i) af[i] = *(const bf16x8*)&lds[p][1][a_off + i * 512];
    if (t + 1 < numK) G2(at + 96, at1 + 96, &lds[pn][3][wsl]);
    __builtin_amdgcn_s_barrier();
    asm volatile("s_waitcnt lgkmcnt(0)" ::: "memory");
    __builtin_amdgcn_s_setprio(1);
    #pragma unroll
    for (int i = 0; i < 4; ++i)
      #pragma unroll
      for (int j = 0; j < 4; ++j)
        acc[i][j] = __builtin_amdgcn_mfma_f32_16x16x32_bf16(af[i], bfr[j], acc[i][j], 0, 0, 0);
    __builtin_amdgcn_s_setprio(0);
    __builtin_amdgcn_s_barrier();

    // ---- phase 1: kk=0, mgroup 1 (B regs reused) ----
    #pragma unroll
    for (int i = 0; i < 4; ++i) af[i] = *(const bf16x8*)&lds[p][1][a_off + (i + 4) * 512];
    if (t + 2 < numK) G2(bt + 128, bt1 + 128, &lds[p][0][wsl]);
    __builtin_amdgcn_s_barrier();
    asm volatile("s_waitcnt lgkmcnt(0)" ::: "memory");
    __builtin_amdgcn_s_setprio(1);
    #pragma unroll
    for (int i = 0; i < 4; ++i)
      #pragma unroll
      for (int j = 0; j < 4; ++j)
        acc[i + 4][j] = __builtin_amdgcn_mfma_f32_16x16x32_bf16(af[i], bfr[j], acc[i + 4][j], 0, 0, 0);
    __builtin_amdgcn_s_setprio(0);
    __builtin_amdgcn_s_barrier();

    // ---- phase 2: kk=1, mgroup 0 ----
    #pragma unroll
    for (int j = 0; j < 4; ++j) bfr[j] = *(const bf16x8*)&lds[p][2][b_off + j * 512];
    #pragma unroll
    for (int i = 0; i < 4; ++i) af[i] = *(const bf16x8*)&lds[p][3][a_off + i * 512];
    if (t + 2 < numK) G2(at + 128, at1 + 128, &lds[p][1][wsl]);
    __builtin_amdgcn_s_barrier();
    asm volatile("s_waitcnt lgkmcnt(0)" ::: "memory");
    __builtin_amdgcn_s_setprio(1);
    #pragma unroll
    for (int i = 0; i < 4; ++i)
      #pragma unroll
      for (int j = 0; j < 4; ++j)
        acc[i][j] = __builtin_amdgcn_mfma_f32_16x16x32_bf16(af[i], bfr[j], acc[i][j], 0, 0, 0);
    __builtin_amdgcn_s_setprio(0);
    __builtin_amdgcn_s_barrier();

    // ---- phase 3: kk=1, mgroup 1 (B regs reused) ----
    #pragma unroll
    for (int i = 0; i < 4; ++i) af[i] = *(const bf16x8*)&lds[p][3][a_off + (i + 4) * 512];
    if (t + 2 < numK) G2(bt + 160, bt1 + 160, &lds[p][2][wsl]);
    __builtin_amdgcn_s_barrier();
    asm volatile("s_waitcnt lgkmcnt(0)" ::: "memory");
    __builtin_amdgcn_s_setprio(1);
    #pragma unroll
    for (int i = 0; i < 4; ++i)
      #pragma unroll
      for (int j = 0; j < 4; ++j)
        acc[i + 4][j] = __builtin_amdgcn_mfma_f32_16x16x32_bf16(af[i], bfr[j], acc[i + 4][j], 0, 0, 0);
    __builtin_amdgcn_s_setprio(0);
    if (t + 2 < numK) { asm volatile("s_waitcnt vmcnt(6)" ::: "memory"); }
    else              { asm volatile("s_waitcnt vmcnt(0)" ::: "memory"); }
    __builtin_amdgcn_s_barrier();

    at += 64; at1 += 64; bt += 64; bt1 += 64;
  }
#undef G2

  // ---------------- epilogue ----------------
  // C/D layout: col = lane&15, row = (lane>>4)*4 + reg
  if (EPI == 0) {
    // wave-private LDS transpose (f32, stride 68) -> contiguous 16B row-segment stores
    float* sb = reinterpret_cast<float*>(&lds[0][0][0]) + wave * 1088;  // 16 rows x 68
    const int seg = lane & 15, rq = lane >> 4;
    const int mrow_base = m0 + wr * 128;
    const int ncol_base = n0 + wc * 64;
    #pragma unroll
    for (int mf = 0; mf < 8; ++mf) {
      #pragma unroll
      for (int nf = 0; nf < 4; ++nf) {
        #pragma unroll
        for (int q = 0; q < 4; ++q)
          sb[(g * 4 + q) * 68 + nf * 16 + r16] = acc[mf][nf][q];
      }
      #pragma unroll
      for (int pz = 0; pz < 4; ++pz) {
        int row = rq + pz * 4;                       // 0..15
        floatx4 v = *reinterpret_cast<const floatx4*>(&sb[row * 68 + seg * 4]);
        int m = mrow_base + mf * 16 + row;
        int n = ncol_base + seg * 4;
        if (n + 4 <= N) {
          __builtin_memcpy(&Cf[(size_t)m * N + n], &v, 16);   // 4B-aligned vector store
        } else {
          #pragma unroll
          for (int e = 0; e < 4; ++e)
            if (n + e < N) Cf[(size_t)m * N + n + e] = v[e];
        }
      }
    }
  } else {
    // wave-private LDS transpose -> 16B bf16x8 stores (full cache lines)
    bf16* sb = &lds[0][0][0] + wave * 1152;   // 16 rows x 72 stride
    const int rr_rd = lane & 15, seg = lane >> 4;
    const int nb = n0 + wc * 64 + r16;
    float bv[4];
    #pragma unroll
    for (int j = 0; j < 4; ++j) bv[j] = bias[nb + j * 16];
    #pragma unroll
    for (int mf = 0; mf < 8; ++mf) {
      #pragma unroll
      for (int j = 0; j < 4; ++j) {
        #pragma unroll
        for (int q = 0; q < 4; ++q) {
          float v = acc[mf][j][q] + bv[j];
          if (EPI == 3) v = gelu_f(v);
          sb[(g * 4 + q) * 72 + j * 16 + r16] = (bf16)v;
        }
      }
      bf16x8 o0 = *(const bf16x8*)&sb[rr_rd * 72 + seg * 16];
      bf16x8 o1 = *(const bf16x8*)&sb[rr_rd * 72 + seg * 16 + 8];
      size_t orow = (size_t)(m0 + wr * 128 + mf * 16 + rr_rd) * N + (n0 + wc * 64 + seg * 16);
      *(bf16x8*)&Cb[orow] = o0;
      *(bf16x8*)&Cb[orow + 8] = o1;
    }
  }
}

// ---------------- legacy 2-phase NT GEMM (proj / fcp: N=768) ----------------
template<int TBM, int MI, int NI, int EPI>
__global__ __launch_bounds__(256) void k_gemm(
    const bf16* __restrict__ A, const bf16* __restrict__ Bt,
    const float* __restrict__ bias, const float* __restrict__ resid,
    float* __restrict__ Cf, bf16* __restrict__ Cb,
    int M, int N, int K) {
  constexpr int BN = 128;
  constexpr int WGN = BN / (NI * 16);
  constexpr int AI = TBM / 32;
  constexpr int BI = BN / 32;
  __shared__ __align__(16) bf16 As[TBM * 64];
  __shared__ __align__(16) bf16 Bs[BN * 64];
  const int m0 = blockIdx.x * TBM, n0 = blockIdx.y * BN;
  const int tid = threadIdx.x;
  const int lane = tid & 63, wave = tid >> 6;
  const int wr = wave / WGN, wc = wave % WGN;
  const int l8 = lane >> 3, s8 = lane & 7;
  const int g = lane >> 4, r16 = lane & 15;

  floatx4 acc[MI][NI] = {};

  const bf16* a_src = A + (size_t)(m0 + l8) * K + s8 * 8;
  const bf16* b_src = Bt + (size_t)(n0 + l8) * K + s8 * 8;

  for (int k0 = 0; k0 < K; k0 += 64) {
    #pragma unroll
    for (int t = 0; t < AI; ++t) {
      int row0 = wave * (TBM / 4) + t * 8;
      gload16(a_src + (size_t)row0 * K + k0, &As[row0 * 64]);
    }
    #pragma unroll
    for (int t = 0; t < BI; ++t) {
      int row0 = wave * 32 + t * 8;
      gload16(b_src + (size_t)row0 * K + k0, &Bs[row0 * 64]);
    }
    __syncthreads();
    #pragma unroll
    for (int kk = 0; kk < 2; ++kk) {
      bf16x8 af[MI], bfr[NI];
      #pragma unroll
      for (int i = 0; i < MI; ++i)
        af[i] = *reinterpret_cast<const bf16x8*>(&As[(wr * MI * 16 + i * 16 + r16) * 64 + g * 8 + kk * 32]);
      #pragma unroll
      for (int j = 0; j < NI; ++j)
        bfr[j] = *reinterpret_cast<const bf16x8*>(&Bs[(wc * NI * 16 + j * 16 + r16) * 64 + g * 8 + kk * 32]);
      #pragma unroll
      for (int i = 0; i < MI; ++i) {
        #pragma unroll
        for (int j = 0; j < NI; ++j)
          acc[i][j] = __builtin_amdgcn_mfma_f32_16x16x32_bf16(af[i], bfr[j], acc[i][j], 0, 0, 0);
      }
    }
    __syncthreads();
  }

  int mb = m0 + wr * MI * 16 + g * 4;
  int nb = n0 + wc * NI * 16 + r16;
  #pragma unroll
  for (int j = 0; j < NI; ++j) {
    int n = nb + j * 16;
    if (n >= N) continue;
    float bv = (EPI >= 2) ? bias[n] : 0.0f;
    #pragma unroll
    for (int i = 0; i < MI; ++i) {
      #pragma unroll
      for (int q = 0; q < 4; ++q) {
        int m = mb + i * 16 + q;
        float v = acc[i][j][q] + bv;
        size_t o = (size_t)m * N + n;
        if (EPI == 2)      Cf[o] = v + resid[o];
        else if (EPI == 3) Cb[o] = (bf16)gelu_f(v);
        else if (EPI == 4) Cb[o] = (bf16)v;
        else               Cf[o] = v;
      }
    }
  }
}

// ---------------- V transpose: qkv_bf V-part -> vt[bh][d][t] bf16 ----------------
__global__ __launch_bounds__(256) void k_vtrans(const bf16* __restrict__ qkv, bf16* __restrict__ vt) {
  __shared__ bf16 tile[64][72];
  int bh = blockIdx.x, t0 = blockIdx.y * 64;
  int b = bh / HNUM, h = bh % HNUM;
  int tid = threadIdx.x;
  int r8 = tid >> 3, s8 = tid & 7;
  #pragma unroll
  for (int p = 0; p < 2; ++p) {
    int row = p * 32 + r8;
    uint4 v = *reinterpret_cast<const uint4*>(
        qkv + (size_t)(b * TDIM + t0 + row) * (3 * CDIM) + 2 * CDIM + h * 64 + s8 * 8);
    *reinterpret_cast<uint4*>(&tile[row][s8 * 8]) = v;
  }
  __syncthreads();
  int d = tid >> 2, q4 = tid & 3;
  #pragma unroll
  for (int half = 0; half < 2; ++half) {
    int t = q4 * 16 + half * 8;
    bf16x8 o;
    #pragma unroll
    for (int u = 0; u < 8; ++u) o[u] = tile[t + u][d];
    *reinterpret_cast<bf16x8*>(vt + (size_t)bh * (64 * TDIM) + (size_t)d * TDIM + t0 + t) = o;
  }
}

// ---------------- MFMA flash attention ----------------
__global__ __launch_bounds__(256) void k_attn(const bf16* __restrict__ qkv,
                                              const bf16* __restrict__ vt,
                                              bf16* __restrict__ y) {
  __shared__ __align__(16) bf16 Ks[64 * 64];
  __shared__ __align__(16) bf16 Vs[64 * 64];
  __shared__ __align__(16) bf16 Ps[64 * 64];
  const int bh = blockIdx.x, qt = blockIdx.y;
  const int b = bh / HNUM, h = bh % HNUM;
  const int tid = threadIdx.x, lane = tid & 63, wave = tid >> 6;
  const int g = lane >> 4, r16 = lane & 15;
  const int w16 = wave * 16;
  const int r8 = tid >> 3, s8 = tid & 7;

  bf16x8 qf[2];
  {
    const bf16* qsrc = qkv + (size_t)(b * TDIM + qt * 64 + w16 + r16) * (3 * CDIM) + h * 64 + g * 8;
    qf[0] = *reinterpret_cast<const bf16x8*>(qsrc);
    qf[1] = *reinterpret_cast<const bf16x8*>(qsrc + 32);
  }

  float m_r[4], l_r[4];
  floatx4 yacc[4] = {};
  #pragma unroll
  for (int q = 0; q < 4; ++q) { m_r[q] = -1e30f; l_r[q] = 0.f; }

  for (int kt = 0; kt <= qt; ++kt) {
    __syncthreads();
    #pragma unroll
    for (int p = 0; p < 2; ++p) {
      int row = p * 32 + r8;
      uint4 kv = *reinterpret_cast<const uint4*>(
          qkv + (size_t)(b * TDIM + kt * 64 + row) * (3 * CDIM) + CDIM + h * 64 + s8 * 8);
      *reinterpret_cast<uint4*>(&Ks[row * 64 + ((s8 ^ (row & 7)) * 8)]) = kv;
      uint4 vv = *reinterpret_cast<const uint4*>(
          vt + (size_t)bh * (64 * TDIM) + (size_t)row * TDIM + kt * 64 + s8 * 8);
      *reinterpret_cast<uint4*>(&Vs[row * 64 + ((s8 ^ (row & 7)) * 8)]) = vv;
    }
    __syncthreads();

    floatx4 sa[4] = {};
    #pragma unroll
    for (int c = 0; c < 2; ++c) {
      bf16x8 kf[4];
      #pragma unroll
      for (int j = 0; j < 4; ++j) {
        int krow = j * 16 + r16;
        kf[j] = *reinterpret_cast<const bf16x8*>(&Ks[krow * 64 + (((g + 4 * c) ^ (krow & 7)) * 8)]);
      }
      #pragma unroll
      for (int j = 0; j < 4; ++j)
        sa[j] = __builtin_amdgcn_mfma_f32_16x16x32_bf16(qf[c], kf[j], sa[j], 0, 0, 0);
    }

    const bool diag = (kt == qt);
    float p_v[4][4];
    #pragma unroll
    for (int q = 0; q < 4; ++q) {
      int qrow = w16 + g * 4 + q;
      float mx = -1e30f;
      #pragma unroll
      for (int j = 0; j < 4; ++j) {
        float s = sa[j][q] * 0.125f;
        if (diag && (r16 + j * 16) > qrow) s = -1e30f;
        p_v[j][q] = s;
        mx = fmaxf(mx, s);
      }
      #pragma unroll
      for (int o = 1; o < 16; o <<= 1) mx = fmaxf(mx, __shfl_xor(mx, o));
      float mnew = fmaxf(m_r[q], mx);
      float ps = 0.f;
      #pragma unroll
      for (int j = 0; j < 4; ++j) {
        float p = __expf(p_v[j][q] - mnew);
        p_v[j][q] = p;
        ps += p;
      }
      #pragma unroll
      for (int o = 1; o < 16; o <<= 1) ps += __shfl_xor(ps, o);
      float alpha = __expf(m_r[q] - mnew);
      m_r[q] = mnew;
      l_r[q] = l_r[q] * alpha + ps;
      #pragma unroll
      for (int j = 0; j < 4; ++j) yacc[j][q] *= alpha;
      #pragma unroll
      for (int j = 0; j < 4; ++j) {
        int col = r16 + j * 16;
        Ps[qrow * 64 + (col ^ ((qrow & 7) << 3))] = (bf16)p_v[j][q];
      }
    }

    #pragma unroll
    for (int ks = 0; ks < 2; ++ks) {
      int prow = w16 + r16;
      bf16x8 pa = *reinterpret_cast<const bf16x8*>(&Ps[prow * 64 + (((g + 4 * ks) ^ (prow & 7)) * 8)]);
      #pragma unroll
      for (int j = 0; j < 4; ++j) {
        int vrow = j * 16 + r16;
        bf16x8 vb = *reinterpret_cast<const bf16x8*>(&Vs[vrow * 64 + (((g + 4 * ks) ^ (vrow & 7)) * 8)]);
        yacc[j] = __builtin_amdgcn_mfma_f32_16x16x32_bf16(pa, vb, yacc[j], 0, 0, 0);
      }
    }
  }

  #pragma unroll
  for (int q = 0; q < 4; ++q) {
    float inv = 1.0f / l_r[q];
    int tok = b * TDIM + qt * 64 + w16 + g * 4 + q;
    #pragma unroll
    for (int j = 0; j < 4; ++j)
      y[(size_t)tok * CDIM + h * 64 + r16 + j * 16] = (bf16)(yacc[j][q] * inv);
  }
}

// ---------------- launcher ----------------
extern "C" void kernel_launch(void* const* d_in, const int* in_sizes, int n_in,
                              void* d_out, int out_size, void* d_ws, size_t ws_size,
                              hipStream_t stream) {
  (void)in_sizes; (void)n_in; (void)out_size;
  const int*   idx    = (const int*)  d_in[0];
  const float* wte    = (const float*)d_in[1];
  const float* wpe    = (const float*)d_in[2];
  const float* ln1_s  = (const float*)d_in[3];
  const float* ln1_b  = (const float*)d_in[4];
  const float* qkv_w  = (const float*)d_in[5];
  const float* qkv_b  = (const float*)d_in[6];
  const float* proj_w = (const float*)d_in[7];
  const float* proj_b = (const float*)d_in[8];
  const float* ln2_s  = (const float*)d_in[9];
  const float* ln2_b  = (const float*)d_in[10];
  const float* fc_w   = (const float*)d_in[11];
  const float* fc_b   = (const float*)d_in[12];
  const float* fcp_w  = (const float*)d_in[13];
  const float* fcp_b  = (const float*)d_in[14];
  const float* lnf_s  = (const float*)d_in[15];
  const float* lnf_b  = (const float*)d_in[16];
  float* logits = (float*)d_out;

  char* base = (char*)d_ws;
  size_t off = 0;
  auto alloc = [&](size_t bytes) -> void* {
    void* p = base + off;
    off += (bytes + 255) & ~(size_t)255;
    return p;
  };
  bf16*  wte_bf  = (bf16*) alloc((size_t)VDIM * CDIM * 2);   // keep FIRST (logits B-tail overreads land in ws)
  bf16*  wq_all  = (bf16*) alloc((size_t)LNUM * 3 * CDIM * CDIM * 2);
  bf16*  wp_all  = (bf16*) alloc((size_t)LNUM * CDIM * CDIM * 2);
  bf16*  wf_all  = (bf16*) alloc((size_t)LNUM * 4 * CDIM * CDIM * 2);
  bf16*  wfp_all = (bf16*) alloc((size_t)LNUM * 4 * CDIM * CDIM * 2);
  float* x       = (float*)alloc((size_t)NTOK * CDIM * 4);
  bf16*  hb      = (bf16*) alloc((size_t)NTOK * CDIM * 2);
  bf16*  qkv_bf  = (bf16*) alloc((size_t)NTOK * 3 * CDIM * 2);
  bf16*  vt      = (bf16*) alloc((size_t)BDIM * HNUM * 64 * TDIM * 2);
  bf16*  yb      = (bf16*) alloc((size_t)NTOK * CDIM * 2);
  bf16*  gb      = (bf16*) alloc((size_t)NTOK * 4 * CDIM * 2);
  if (off > ws_size) return;

  k_cvt_bf16<<<4096, 256, 0, stream>>>(wte, wte_bf, (long)VDIM * CDIM);
  k_trans_all<<<LNUM * TILES_LAYER, 256, 0, stream>>>(qkv_w, proj_w, fc_w, fcp_w,
                                                      wq_all, wp_all, wf_all, wfp_all);
  k_embed<<<NTOK, 256, 0, stream>>>(idx, wte, wpe, x);

  for (int l = 0; l < LNUM; ++l) {
    const bf16* wq  = wq_all  + (size_t)l * 3 * CDIM * CDIM;
    const bf16* wp  = wp_all  + (size_t)l * CDIM * CDIM;
    const bf16* wf  = wf_all  + (size_t)l * 4 * CDIM * CDIM;
    const bf16* wfp = wfp_all + (size_t)l * 4 * CDIM * CDIM;

    k_layernorm<<<NTOK, 256, 0, stream>>>(x, ln1_s + l*CDIM, ln1_b + l*CDIM, hb);
    k_gemm8<4><<<16 * 9, 512, 0, stream>>>(hb, wq, qkv_b + (size_t)l*3*CDIM, nullptr, qkv_bf, 3*CDIM, CDIM);
    k_vtrans<<<dim3(BDIM*HNUM, TDIM/64), 256, 0, stream>>>(qkv_bf, vt);
    k_attn<<<dim3(BDIM*HNUM, TDIM/64), 256, 0, stream>>>(qkv_bf, vt, yb);
    k_gemm<64,4,2,2><<<dim3(NTOK/64, 6), 256, 0, stream>>>(yb, wp, proj_b + (size_t)l*CDIM, x, x, nullptr, NTOK, CDIM, CDIM);
    k_layernorm<<<NTOK, 256, 0, stream>>>(x, ln2_s + l*CDIM, ln2_b + l*CDIM, hb);
    k_gemm8<3><<<16 * 12, 512, 0, stream>>>(hb, wf, fc_b + (size_t)l*4*CDIM, nullptr, gb, 4*CDIM, CDIM);
    k_gemm<64,4,2,2><<<dim3(NTOK/64, 6), 256, 0, stream>>>(gb, wfp, fcp_b + (size_t)l*CDIM, x, x, nullptr, NTOK, CDIM, 4*CDIM);
  }

  k_layernorm<<<NTOK, 256, 0, stream>>>(x, lnf_s, lnf_b, hb);
  int ntile = (VDIM + 255) / 256;  // 197; tail masked in epilogue, staging overreads stay in ws
  k_gemm8<0><<<16 * ntile, 512, 0, stream>>>(hb, wte_bf, nullptr, logits, nullptr, VDIM, CDIM);
}

// Round 8
// 1778.651 us; speedup vs baseline: 1.3038x; 1.0341x over previous
//
#include <hip/hip_runtime.h>
#include <math.h>

#define LNUM 6
#define HNUM 12
#define CDIM 768
#define VDIM 50257
#define BDIM 4
#define TDIM 1024
#define NTOK 4096   // B*T

typedef __bf16 bf16;
typedef __bf16 bf16x8 __attribute__((ext_vector_type(8)));
typedef float  floatx4 __attribute__((ext_vector_type(4)));
typedef unsigned int u32;

// async global->LDS, 16B per lane. LDS dest must be wave-uniform base; HW adds lane*16.
__device__ inline void gload16(const bf16* gsrc, bf16* lds) {
  __builtin_amdgcn_global_load_lds(
      (const __attribute__((address_space(1))) u32*)gsrc,
      (__attribute__((address_space(3))) u32*)lds, 16, 0, 0);
}

// ---------------- fp32 -> bf16 bulk convert (wte) ----------------
__global__ void k_cvt_bf16(const float* __restrict__ in, bf16* __restrict__ out, long n) {
  long i = ((long)blockIdx.x * blockDim.x + threadIdx.x) * 4;
  long stride = (long)gridDim.x * blockDim.x * 4;
  for (; i < n; i += stride) {
    float4 v = *reinterpret_cast<const float4*>(in + i);
    bf16 b0 = (bf16)v.x, b1 = (bf16)v.y, b2 = (bf16)v.z, b3 = (bf16)v.w;
    ushort4 pk;
    pk.x = __builtin_bit_cast(unsigned short, b0);
    pk.y = __builtin_bit_cast(unsigned short, b1);
    pk.z = __builtin_bit_cast(unsigned short, b2);
    pk.w = __builtin_bit_cast(unsigned short, b3);
    *reinterpret_cast<ushort4*>(out + i) = pk;
  }
}

// -------- batched transpose+convert for ALL layer weights (one launch) --------
#define TILES_QKV  1728
#define TILES_PROJ 576
#define TILES_FC   2304
#define TILES_FCP  2304
#define TILES_LAYER (TILES_QKV + TILES_PROJ + TILES_FC + TILES_FCP)

__global__ __launch_bounds__(256) void k_trans_all(
    const float* __restrict__ qkv_w, const float* __restrict__ proj_w,
    const float* __restrict__ fc_w, const float* __restrict__ fcp_w,
    bf16* __restrict__ wq, bf16* __restrict__ wp,
    bf16* __restrict__ wf, bf16* __restrict__ wfp) {
  __shared__ float tile[32][33];
  int bid = blockIdx.x;
  int layer = bid / TILES_LAYER, r = bid % TILES_LAYER;
  const float* src; bf16* dst; int K, N, tx, ty;
  if (r < TILES_QKV) {
    src = qkv_w + (size_t)layer * CDIM * 3 * CDIM; dst = wq + (size_t)layer * CDIM * 3 * CDIM;
    K = CDIM; N = 3 * CDIM; tx = r % 72; ty = r / 72;
  } else if (r < TILES_QKV + TILES_PROJ) {
    r -= TILES_QKV;
    src = proj_w + (size_t)layer * CDIM * CDIM; dst = wp + (size_t)layer * CDIM * CDIM;
    K = CDIM; N = CDIM; tx = r % 24; ty = r / 24;
  } else if (r < TILES_QKV + TILES_PROJ + TILES_FC) {
    r -= TILES_QKV + TILES_PROJ;
    src = fc_w + (size_t)layer * CDIM * 4 * CDIM; dst = wf + (size_t)layer * CDIM * 4 * CDIM;
    K = CDIM; N = 4 * CDIM; tx = r % 96; ty = r / 96;
  } else {
    r -= TILES_QKV + TILES_PROJ + TILES_FC;
    src = fcp_w + (size_t)layer * 4 * CDIM * CDIM; dst = wfp + (size_t)layer * 4 * CDIM * CDIM;
    K = 4 * CDIM; N = CDIM; tx = r % 24; ty = r / 24;
  }
  int n0 = tx * 32, k0 = ty * 32;
  int nx = threadIdx.x & 31, tyy = threadIdx.x >> 5;
  #pragma unroll
  for (int p = 0; p < 4; ++p) {
    int k = tyy + p * 8;
    tile[k][nx] = src[(size_t)(k0 + k) * N + n0 + nx];
  }
  __syncthreads();
  #pragma unroll
  for (int p = 0; p < 4; ++p) {
    int n = tyy + p * 8;
    dst[(size_t)(n0 + n) * K + k0 + nx] = (bf16)tile[nx][n];
  }
}

// ---------------- embedding ----------------
__global__ void k_embed(const int* __restrict__ idx, const float* __restrict__ wte,
                        const float* __restrict__ wpe, float* __restrict__ x) {
  int tok = blockIdx.x;
  int t = tok & (TDIM - 1);
  int id = idx[tok];
  const float* a = wte + (size_t)id * CDIM;
  const float* p = wpe + (size_t)t * CDIM;
  float* o = x + (size_t)tok * CDIM;
  for (int c = threadIdx.x; c < CDIM; c += 256) o[c] = a[c] + p[c];
}

// ---------------- layernorm: fp32 in -> bf16 out ----------------
__global__ __launch_bounds__(256) void k_layernorm(const float* __restrict__ x,
    const float* __restrict__ sc, const float* __restrict__ bi, bf16* __restrict__ out) {
  __shared__ float red[8];
  int row = blockIdx.x;
  const float* xr = x + (size_t)row * CDIM;
  int t = threadIdx.x;
  float v0 = xr[t], v1 = xr[t + 256], v2 = xr[t + 512];
  float s = v0 + v1 + v2;
  #pragma unroll
  for (int o = 32; o > 0; o >>= 1) s += __shfl_down(s, o);
  if ((t & 63) == 0) red[t >> 6] = s;
  __syncthreads();
  float mean = (red[0] + red[1] + red[2] + red[3]) * (1.0f / CDIM);
  float d0 = v0 - mean, d1 = v1 - mean, d2 = v2 - mean;
  float q = d0 * d0 + d1 * d1 + d2 * d2;
  #pragma unroll
  for (int o = 32; o > 0; o >>= 1) q += __shfl_down(q, o);
  if ((t & 63) == 0) red[4 + (t >> 6)] = q;
  __syncthreads();
  float var = (red[4] + red[5] + red[6] + red[7]) * (1.0f / CDIM);
  float rs = rsqrtf(var + 1e-5f);
  bf16* orow = out + (size_t)row * CDIM;
  orow[t]       = (bf16)(d0 * rs * sc[t]       + bi[t]);
  orow[t + 256] = (bf16)(d1 * rs * sc[t + 256] + bi[t + 256]);
  orow[t + 512] = (bf16)(d2 * rs * sc[t + 512] + bi[t + 512]);
}

__device__ inline float gelu_f(float x) {
  float x3 = x * x * x;
  return 0.5f * x * (1.0f + tanhf(0.7978845608028654f * (x + 0.044715f * x3)));
}

// ================= TBMx256 BK=32 pipelined MFMA GEMM (T2-swizzled LDS) =================
// C[4096,N] = A[4096,K] * Bt[N,K]^T.  BN=256, BK=32, 512 threads (8 waves, 2Mx4N).
// LDS: Bs[2][256x32] + As[2][TBMx32]  (TBM=256: 64KB -> 2 blocks/CU; TBM=128: 48KB -> 3/CU).
// Per tile t (parity p): 2 phases x 16(or 8) MFMA.
//   ph0: ds_read B[p]+A[p].lo | stage A(t+1)->As[pn] | bar | lgkm0 | MFMA | bar
//   ph1: ds_read A[p].hi      | stage B(t+2)->Bs[p]  | bar | lgkm0 | MFMA | vmcnt(2) | bar
// Lifetimes: A[pn] last read t-1.ph1 (barrier-sep); B[p] reads issue ph0 (regs reused ph1).
// vmcnt(2) at t-end retires A(t+1),B(t+1) (only B(t+2)'s 2 loads newer). Tail -> vmcnt(0).
// T2 swizzle pair (rule 21): source col permute ((l&3)^((l>>3)&3)) + read XOR (g^((r16>>1)&3)).
// EPI: 0 ->f32 via LDS transpose + 16B stores (N-tail guarded), 3 +bias+gelu ->bf16, 4 +bias ->bf16
template<int TBM, int EPI>
__global__ __launch_bounds__(512, 1) void k_gemm8(
    const bf16* __restrict__ A, const bf16* __restrict__ Bt,
    const float* __restrict__ bias,
    float* __restrict__ Cf, bf16* __restrict__ Cb,
    int N, int K) {
  constexpr int MI = TBM / 32;        // m-frags per wave
  constexpr int MH = MI / 2;          // per phase
  constexpr int MTILES = 4096 / TBM;
  __shared__ __align__(16) bf16 smem[2 * 8192 + 2 * TBM * 32];
  bf16* Bs = smem;                    // [2][8192]
  bf16* As = smem + 2 * 8192;         // [2][TBM*32]
  const int nwg = gridDim.x;          // divisible by 8
  const int id = blockIdx.x;
  const int swz = (id & 7) * (nwg >> 3) + (id >> 3);   // XCD-chunked (bijective, nwg%8==0)
  const int m0 = (swz % MTILES) * TBM;
  const int n0 = (swz / MTILES) * 256;
  const int tid = threadIdx.x, lane = tid & 63, wave = tid >> 6;
  const int wr = wave >> 2, wc = wave & 3;             // wave grid 2(M) x 4(N)
  const int g = lane >> 4, r16 = lane & 15;
  const int numK = K >> 5;                             // BK=32
  const int wsl = wave * 512;

  const int srow = wave * 16 + (lane >> 2);
  const int scol = ((lane & 3) ^ ((lane >> 3) & 3)) * 8;   // T2 source permute
  const bf16* at  = A  + (size_t)(m0 + srow) * K + scol;
  const bf16* at1 = A  + (size_t)(m0 + srow + 128) * K + scol;   // deref'd only if TBM==256
  const bf16* bt  = Bt + (size_t)(n0 + srow) * K + scol;
  const bf16* bt1 = Bt + (size_t)(n0 + srow + 128) * K + scol;
  const int sw = (g ^ ((r16 >> 1) & 3)) * 8;               // T2 read XOR
  const int a_off = (wr * (TBM / 2) + r16) * 32 + sw;
  const int b_off = (wc * 64 + r16) * 32 + sw;

  floatx4 acc[MI][4] = {};

#define STB(s0, s1, pb) do { gload16((s0), Bs + (pb) * 8192 + wsl); \
                             gload16((s1), Bs + (pb) * 8192 + wsl + 4096); } while (0)
#define STA(s0, s1, pb) do { gload16((s0), As + (pb) * TBM * 32 + wsl); \
                             if constexpr (TBM == 256) gload16((s1), As + (pb) * TBM * 32 + wsl + 4096); } while (0)

  // prologue: B(0), A(0), B(1); need first two landed -> vmcnt(2)
  STB(bt, bt1, 0);
  STA(at, at1, 0);
  STB(bt + 32, bt1 + 32, 1);
  asm volatile("s_waitcnt vmcnt(2)" ::: "memory");
  __builtin_amdgcn_s_barrier();

  for (int t = 0; t < numK; ++t) {
    const int p = t & 1, pn = p ^ 1;
    bf16x8 af[MH], bfr[4];

    // ---- phase 0: mgroup 0 ----
    #pragma unroll
    for (int j = 0; j < 4; ++j) bfr[j] = *(const bf16x8*)&Bs[p * 8192 + b_off + j * 512];
    #pragma unroll
    for (int i = 0; i < MH; ++i) af[i] = *(const bf16x8*)&As[p * TBM * 32 + a_off + i * 512];
    if (t + 1 < numK) STA(at + 32, at1 + 32, pn);
    __builtin_amdgcn_s_barrier();
    asm volatile("s_waitcnt lgkmcnt(0)" ::: "memory");
    __builtin_amdgcn_s_setprio(1);
    #pragma unroll
    for (int i = 0; i < MH; ++i)
      #pragma unroll
      for (int j = 0; j < 4; ++j)
        acc[i][j] = __builtin_amdgcn_mfma_f32_16x16x32_bf16(af[i], bfr[j], acc[i][j], 0, 0, 0);
    __builtin_amdgcn_s_setprio(0);
    __builtin_amdgcn_s_barrier();

    // ---- phase 1: mgroup 1 (B regs reused) ----
    #pragma unroll
    for (int i = 0; i < MH; ++i) af[i] = *(const bf16x8*)&As[p * TBM * 32 + a_off + (i + MH) * 512];
    if (t + 2 < numK) STB(bt + 64, bt1 + 64, p);
    __builtin_amdgcn_s_barrier();
    asm volatile("s_waitcnt lgkmcnt(0)" ::: "memory");
    __builtin_amdgcn_s_setprio(1);
    #pragma unroll
    for (int i = 0; i < MH; ++i)
      #pragma unroll
      for (int j = 0; j < 4; ++j)
        acc[i + MH][j] = __builtin_amdgcn_mfma_f32_16x16x32_bf16(af[i], bfr[j], acc[i + MH][j], 0, 0, 0);
    __builtin_amdgcn_s_setprio(0);
    if (t + 2 < numK) { asm volatile("s_waitcnt vmcnt(2)" ::: "memory"); }
    else              { asm volatile("s_waitcnt vmcnt(0)" ::: "memory"); }
    __builtin_amdgcn_s_barrier();

    at += 32; at1 += 32; bt += 32; bt1 += 32;
  }
#undef STB
#undef STA

  // ---------------- epilogue ----------------
  // C/D layout: col = lane&15, row = (lane>>4)*4 + reg
  if (EPI == 0) {
    // wave-private LDS transpose (f32, stride 68) -> contiguous 16B row-segment stores
    float* sb = reinterpret_cast<float*>(smem) + wave * 1088;  // 16 rows x 68
    const int seg = lane & 15, rq = lane >> 4;
    const int mrow_base = m0 + wr * (TBM / 2);
    const int ncol_base = n0 + wc * 64;
    #pragma unroll
    for (int mf = 0; mf < MI; ++mf) {
      #pragma unroll
      for (int nf = 0; nf < 4; ++nf) {
        #pragma unroll
        for (int q = 0; q < 4; ++q)
          sb[(g * 4 + q) * 68 + nf * 16 + r16] = acc[mf][nf][q];
      }
      #pragma unroll
      for (int pz = 0; pz < 4; ++pz) {
        int row = rq + pz * 4;                       // 0..15
        floatx4 v = *reinterpret_cast<const floatx4*>(&sb[row * 68 + seg * 4]);
        int m = mrow_base + mf * 16 + row;
        int n = ncol_base + seg * 4;
        if (n + 4 <= N) {
          __builtin_memcpy(&Cf[(size_t)m * N + n], &v, 16);   // 4B-aligned vector store
        } else {
          #pragma unroll
          for (int e = 0; e < 4; ++e)
            if (n + e < N) Cf[(size_t)m * N + n + e] = v[e];
        }
      }
    }
  } else {
    // wave-private LDS transpose -> 16B bf16x8 stores (full cache lines)
    bf16* sb = smem + wave * 1152;   // 16 rows x 72 stride
    const int rr_rd = lane & 15, seg = lane >> 4;
    const int nb = n0 + wc * 64 + r16;
    float bv[4];
    #pragma unroll
    for (int j = 0; j < 4; ++j) bv[j] = bias[nb + j * 16];
    #pragma unroll
    for (int mf = 0; mf < MI; ++mf) {
      #pragma unroll
      for (int j = 0; j < 4; ++j) {
        #pragma unroll
        for (int q = 0; q < 4; ++q) {
          float v = acc[mf][j][q] + bv[j];
          if (EPI == 3) v = gelu_f(v);
          sb[(g * 4 + q) * 72 + j * 16 + r16] = (bf16)v;
        }
      }
      bf16x8 o0 = *(const bf16x8*)&sb[rr_rd * 72 + seg * 16];
      bf16x8 o1 = *(const bf16x8*)&sb[rr_rd * 72 + seg * 16 + 8];
      size_t orow = (size_t)(m0 + wr * (TBM / 2) + mf * 16 + rr_rd) * N + (n0 + wc * 64 + seg * 16);
      *(bf16x8*)&Cb[orow] = o0;
      *(bf16x8*)&Cb[orow + 8] = o1;
    }
  }
}

// ---------------- legacy 2-phase NT GEMM (proj / fcp: N=768) ----------------
template<int TBM, int MI, int NI, int EPI>
__global__ __launch_bounds__(256) void k_gemm(
    const bf16* __restrict__ A, const bf16* __restrict__ Bt,
    const float* __restrict__ bias, const float* __restrict__ resid,
    float* __restrict__ Cf, bf16* __restrict__ Cb,
    int M, int N, int K) {
  constexpr int BN = 128;
  constexpr int WGN = BN / (NI * 16);
  constexpr int AI = TBM / 32;
  constexpr int BI = BN / 32;
  __shared__ __align__(16) bf16 As[TBM * 64];
  __shared__ __align__(16) bf16 Bs[BN * 64];
  const int m0 = blockIdx.x * TBM, n0 = blockIdx.y * BN;
  const int tid = threadIdx.x;
  const int lane = tid & 63, wave = tid >> 6;
  const int wr = wave / WGN, wc = wave % WGN;
  const int l8 = lane >> 3, s8 = lane & 7;
  const int g = lane >> 4, r16 = lane & 15;

  floatx4 acc[MI][NI] = {};

  const bf16* a_src = A + (size_t)(m0 + l8) * K + s8 * 8;
  const bf16* b_src = Bt + (size_t)(n0 + l8) * K + s8 * 8;

  for (int k0 = 0; k0 < K; k0 += 64) {
    #pragma unroll
    for (int t = 0; t < AI; ++t) {
      int row0 = wave * (TBM / 4) + t * 8;
      gload16(a_src + (size_t)row0 * K + k0, &As[row0 * 64]);
    }
    #pragma unroll
    for (int t = 0; t < BI; ++t) {
      int row0 = wave * 32 + t * 8;
      gload16(b_src + (size_t)row0 * K + k0, &Bs[row0 * 64]);
    }
    __syncthreads();
    #pragma unroll
    for (int kk = 0; kk < 2; ++kk) {
      bf16x8 af[MI], bfr[NI];
      #pragma unroll
      for (int i = 0; i < MI; ++i)
        af[i] = *reinterpret_cast<const bf16x8*>(&As[(wr * MI * 16 + i * 16 + r16) * 64 + g * 8 + kk * 32]);
      #pragma unroll
      for (int j = 0; j < NI; ++j)
        bfr[j] = *reinterpret_cast<const bf16x8*>(&Bs[(wc * NI * 16 + j * 16 + r16) * 64 + g * 8 + kk * 32]);
      #pragma unroll
      for (int i = 0; i < MI; ++i) {
        #pragma unroll
        for (int j = 0; j < NI; ++j)
          acc[i][j] = __builtin_amdgcn_mfma_f32_16x16x32_bf16(af[i], bfr[j], acc[i][j], 0, 0, 0);
      }
    }
    __syncthreads();
  }

  int mb = m0 + wr * MI * 16 + g * 4;
  int nb = n0 + wc * NI * 16 + r16;
  #pragma unroll
  for (int j = 0; j < NI; ++j) {
    int n = nb + j * 16;
    if (n >= N) continue;
    float bv = (EPI >= 2) ? bias[n] : 0.0f;
    #pragma unroll
    for (int i = 0; i < MI; ++i) {
      #pragma unroll
      for (int q = 0; q < 4; ++q) {
        int m = mb + i * 16 + q;
        float v = acc[i][j][q] + bv;
        size_t o = (size_t)m * N + n;
        if (EPI == 2)      Cf[o] = v + resid[o];
        else if (EPI == 3) Cb[o] = (bf16)gelu_f(v);
        else if (EPI == 4) Cb[o] = (bf16)v;
        else               Cf[o] = v;
      }
    }
  }
}

// ---------------- V transpose: qkv_bf V-part -> vt[bh][d][t] bf16 ----------------
__global__ __launch_bounds__(256) void k_vtrans(const bf16* __restrict__ qkv, bf16* __restrict__ vt) {
  __shared__ bf16 tile[64][72];
  int bh = blockIdx.x, t0 = blockIdx.y * 64;
  int b = bh / HNUM, h = bh % HNUM;
  int tid = threadIdx.x;
  int r8 = tid >> 3, s8 = tid & 7;
  #pragma unroll
  for (int p = 0; p < 2; ++p) {
    int row = p * 32 + r8;
    uint4 v = *reinterpret_cast<const uint4*>(
        qkv + (size_t)(b * TDIM + t0 + row) * (3 * CDIM) + 2 * CDIM + h * 64 + s8 * 8);
    *reinterpret_cast<uint4*>(&tile[row][s8 * 8]) = v;
  }
  __syncthreads();
  int d = tid >> 2, q4 = tid & 3;
  #pragma unroll
  for (int half = 0; half < 2; ++half) {
    int t = q4 * 16 + half * 8;
    bf16x8 o;
    #pragma unroll
    for (int u = 0; u < 8; ++u) o[u] = tile[t + u][d];
    *reinterpret_cast<bf16x8*>(vt + (size_t)bh * (64 * TDIM) + (size_t)d * TDIM + t0 + t) = o;
  }
}

// ---------------- MFMA flash attention ----------------
__global__ __launch_bounds__(256) void k_attn(const bf16* __restrict__ qkv,
                                              const bf16* __restrict__ vt,
                                              bf16* __restrict__ y) {
  __shared__ __align__(16) bf16 Ks[64 * 64];
  __shared__ __align__(16) bf16 Vs[64 * 64];
  __shared__ __align__(16) bf16 Ps[64 * 64];
  const int bh = blockIdx.x, qt = blockIdx.y;
  const int b = bh / HNUM, h = bh % HNUM;
  const int tid = threadIdx.x, lane = tid & 63, wave = tid >> 6;
  const int g = lane >> 4, r16 = lane & 15;
  const int w16 = wave * 16;
  const int r8 = tid >> 3, s8 = tid & 7;

  bf16x8 qf[2];
  {
    const bf16* qsrc = qkv + (size_t)(b * TDIM + qt * 64 + w16 + r16) * (3 * CDIM) + h * 64 + g * 8;
    qf[0] = *reinterpret_cast<const bf16x8*>(qsrc);
    qf[1] = *reinterpret_cast<const bf16x8*>(qsrc + 32);
  }

  float m_r[4], l_r[4];
  floatx4 yacc[4] = {};
  #pragma unroll
  for (int q = 0; q < 4; ++q) { m_r[q] = -1e30f; l_r[q] = 0.f; }

  for (int kt = 0; kt <= qt; ++kt) {
    __syncthreads();
    #pragma unroll
    for (int p = 0; p < 2; ++p) {
      int row = p * 32 + r8;
      uint4 kv = *reinterpret_cast<const uint4*>(
          qkv + (size_t)(b * TDIM + kt * 64 + row) * (3 * CDIM) + CDIM + h * 64 + s8 * 8);
      *reinterpret_cast<uint4*>(&Ks[row * 64 + ((s8 ^ (row & 7)) * 8)]) = kv;
      uint4 vv = *reinterpret_cast<const uint4*>(
          vt + (size_t)bh * (64 * TDIM) + (size_t)row * TDIM + kt * 64 + s8 * 8);
      *reinterpret_cast<uint4*>(&Vs[row * 64 + ((s8 ^ (row & 7)) * 8)]) = vv;
    }
    __syncthreads();

    floatx4 sa[4] = {};
    #pragma unroll
    for (int c = 0; c < 2; ++c) {
      bf16x8 kf[4];
      #pragma unroll
      for (int j = 0; j < 4; ++j) {
        int krow = j * 16 + r16;
        kf[j] = *reinterpret_cast<const bf16x8*>(&Ks[krow * 64 + (((g + 4 * c) ^ (krow & 7)) * 8)]);
      }
      #pragma unroll
      for (int j = 0; j < 4; ++j)
        sa[j] = __builtin_amdgcn_mfma_f32_16x16x32_bf16(qf[c], kf[j], sa[j], 0, 0, 0);
    }

    const bool diag = (kt == qt);
    float p_v[4][4];
    #pragma unroll
    for (int q = 0; q < 4; ++q) {
      int qrow = w16 + g * 4 + q;
      float mx = -1e30f;
      #pragma unroll
      for (int j = 0; j < 4; ++j) {
        float s = sa[j][q] * 0.125f;
        if (diag && (r16 + j * 16) > qrow) s = -1e30f;
        p_v[j][q] = s;
        mx = fmaxf(mx, s);
      }
      #pragma unroll
      for (int o = 1; o < 16; o <<= 1) mx = fmaxf(mx, __shfl_xor(mx, o));
      float mnew = fmaxf(m_r[q], mx);
      float ps = 0.f;
      #pragma unroll
      for (int j = 0; j < 4; ++j) {
        float p = __expf(p_v[j][q] - mnew);
        p_v[j][q] = p;
        ps += p;
      }
      #pragma unroll
      for (int o = 1; o < 16; o <<= 1) ps += __shfl_xor(ps, o);
      float alpha = __expf(m_r[q] - mnew);
      m_r[q] = mnew;
      l_r[q] = l_r[q] * alpha + ps;
      #pragma unroll
      for (int j = 0; j < 4; ++j) yacc[j][q] *= alpha;
      #pragma unroll
      for (int j = 0; j < 4; ++j) {
        int col = r16 + j * 16;
        Ps[qrow * 64 + (col ^ ((qrow & 7) << 3))] = (bf16)p_v[j][q];
      }
    }

    #pragma unroll
    for (int ks = 0; ks < 2; ++ks) {
      int prow = w16 + r16;
      bf16x8 pa = *reinterpret_cast<const bf16x8*>(&Ps[prow * 64 + (((g + 4 * ks) ^ (prow & 7)) * 8)]);
      #pragma unroll
      for (int j = 0; j < 4; ++j) {
        int vrow = j * 16 + r16;
        bf16x8 vb = *reinterpret_cast<const bf16x8*>(&Vs[vrow * 64 + (((g + 4 * ks) ^ (vrow & 7)) * 8)]);
        yacc[j] = __builtin_amdgcn_mfma_f32_16x16x32_bf16(pa, vb, yacc[j], 0, 0, 0);
      }
    }
  }

  #pragma unroll
  for (int q = 0; q < 4; ++q) {
    float inv = 1.0f / l_r[q];
    int tok = b * TDIM + qt * 64 + w16 + g * 4 + q;
    #pragma unroll
    for (int j = 0; j < 4; ++j)
      y[(size_t)tok * CDIM + h * 64 + r16 + j * 16] = (bf16)(yacc[j][q] * inv);
  }
}

// ---------------- launcher ----------------
extern "C" void kernel_launch(void* const* d_in, const int* in_sizes, int n_in,
                              void* d_out, int out_size, void* d_ws, size_t ws_size,
                              hipStream_t stream) {
  (void)in_sizes; (void)n_in; (void)out_size;
  const int*   idx    = (const int*)  d_in[0];
  const float* wte    = (const float*)d_in[1];
  const float* wpe    = (const float*)d_in[2];
  const float* ln1_s  = (const float*)d_in[3];
  const float* ln1_b  = (const float*)d_in[4];
  const float* qkv_w  = (const float*)d_in[5];
  const float* qkv_b  = (const float*)d_in[6];
  const float* proj_w = (const float*)d_in[7];
  const float* proj_b = (const float*)d_in[8];
  const float* ln2_s  = (const float*)d_in[9];
  const float* ln2_b  = (const float*)d_in[10];
  const float* fc_w   = (const float*)d_in[11];
  const float* fc_b   = (const float*)d_in[12];
  const float* fcp_w  = (const float*)d_in[13];
  const float* fcp_b  = (const float*)d_in[14];
  const float* lnf_s  = (const float*)d_in[15];
  const float* lnf_b  = (const float*)d_in[16];
  float* logits = (float*)d_out;

  char* base = (char*)d_ws;
  size_t off = 0;
  auto alloc = [&](size_t bytes) -> void* {
    void* p = base + off;
    off += (bytes + 255) & ~(size_t)255;
    return p;
  };
  bf16*  wte_bf  = (bf16*) alloc((size_t)VDIM * CDIM * 2);   // keep FIRST (logits B-tail overreads land in ws)
  bf16*  wq_all  = (bf16*) alloc((size_t)LNUM * 3 * CDIM * CDIM * 2);
  bf16*  wp_all  = (bf16*) alloc((size_t)LNUM * CDIM * CDIM * 2);
  bf16*  wf_all  = (bf16*) alloc((size_t)LNUM * 4 * CDIM * CDIM * 2);
  bf16*  wfp_all = (bf16*) alloc((size_t)LNUM * 4 * CDIM * CDIM * 2);
  float* x       = (float*)alloc((size_t)NTOK * CDIM * 4);
  bf16*  hb      = (bf16*) alloc((size_t)NTOK * CDIM * 2);
  bf16*  qkv_bf  = (bf16*) alloc((size_t)NTOK * 3 * CDIM * 2);
  bf16*  vt      = (bf16*) alloc((size_t)BDIM * HNUM * 64 * TDIM * 2);
  bf16*  yb      = (bf16*) alloc((size_t)NTOK * CDIM * 2);
  bf16*  gb      = (bf16*) alloc((size_t)NTOK * 4 * CDIM * 2);
  if (off > ws_size) return;

  k_cvt_bf16<<<4096, 256, 0, stream>>>(wte, wte_bf, (long)VDIM * CDIM);
  k_trans_all<<<LNUM * TILES_LAYER, 256, 0, stream>>>(qkv_w, proj_w, fc_w, fcp_w,
                                                      wq_all, wp_all, wf_all, wfp_all);
  k_embed<<<NTOK, 256, 0, stream>>>(idx, wte, wpe, x);

  for (int l = 0; l < LNUM; ++l) {
    const bf16* wq  = wq_all  + (size_t)l * 3 * CDIM * CDIM;
    const bf16* wp  = wp_all  + (size_t)l * CDIM * CDIM;
    const bf16* wf  = wf_all  + (size_t)l * 4 * CDIM * CDIM;
    const bf16* wfp = wfp_all + (size_t)l * 4 * CDIM * CDIM;

    k_layernorm<<<NTOK, 256, 0, stream>>>(x, ln1_s + l*CDIM, ln1_b + l*CDIM, hb);
    k_gemm8<128,4><<<32 * 9, 512, 0, stream>>>(hb, wq, qkv_b + (size_t)l*3*CDIM, nullptr, qkv_bf, 3*CDIM, CDIM);
    k_vtrans<<<dim3(BDIM*HNUM, TDIM/64), 256, 0, stream>>>(qkv_bf, vt);
    k_attn<<<dim3(BDIM*HNUM, TDIM/64), 256, 0, stream>>>(qkv_bf, vt, yb);
    k_gemm<64,4,2,2><<<dim3(NTOK/64, 6), 256, 0, stream>>>(yb, wp, proj_b + (size_t)l*CDIM, x, x, nullptr, NTOK, CDIM, CDIM);
    k_layernorm<<<NTOK, 256, 0, stream>>>(x, ln2_s + l*CDIM, ln2_b + l*CDIM, hb);
    k_gemm8<128,3><<<32 * 12, 512, 0, stream>>>(hb, wf, fc_b + (size_t)l*4*CDIM, nullptr, gb, 4*CDIM, CDIM);
    k_gemm<64,4,2,2><<<dim3(NTOK/64, 6), 256, 0, stream>>>(gb, wfp, fcp_b + (size_t)l*CDIM, x, x, nullptr, NTOK, CDIM, 4*CDIM);
  }

  k_layernorm<<<NTOK, 256, 0, stream>>>(x, lnf_s, lnf_b, hb);
  int ntile = (VDIM + 255) / 256;  // 197; tail masked in epilogue, staging overreads stay in ws
  k_gemm8<256,0><<<16 * ntile, 512, 0, stream>>>(hb, wte_bf, nullptr, logits, nullptr, VDIM, CDIM);
}